// Round 1
// baseline (7442.863 us; speedup 1.0000x reference)
//
#include <hip/hip_runtime.h>
#include <stdint.h>

typedef short short8 __attribute__((ext_vector_type(8)));
typedef float floatx16 __attribute__((ext_vector_type(16)));
typedef unsigned int uint32;

#define NPTS (4 * 65536)
#define RGB_OFF (NPTS * 3)

// ---------- helpers ----------
__device__ __forceinline__ uint16_t bf_rne(float f) {
  uint32 u = __float_as_uint(f);
  u += 0x7FFFu + ((u >> 16) & 1u);
  return (uint16_t)(u >> 16);
}
// round-half-up bf16 pair pack (cheap: 1 add per value + merge)
__device__ __forceinline__ uint32 pack2(float a, float b) {
  uint32 ua = (__float_as_uint(a) + 0x8000u) >> 16;
  uint32 ub = (__float_as_uint(b) + 0x8000u) & 0xFFFF0000u;
  return ua | ub;
}
__device__ __forceinline__ void gacc(const uint16_t* p, float w, float* acc) {
  uint4 q = *(const uint4*)p;
  acc[0] += w * __uint_as_float(q.x << 16);
  acc[1] += w * __uint_as_float(q.x & 0xFFFF0000u);
  acc[2] += w * __uint_as_float(q.y << 16);
  acc[3] += w * __uint_as_float(q.y & 0xFFFF0000u);
  acc[4] += w * __uint_as_float(q.z << 16);
  acc[5] += w * __uint_as_float(q.z & 0xFFFF0000u);
  acc[6] += w * __uint_as_float(q.w << 16);
  acc[7] += w * __uint_as_float(q.w & 0xFFFF0000u);
}

// ---------- kernel 1: triplane (12,32,256,256) f32 -> (12,256,256,32) bf16 ----------
__global__ __launch_bounds__(256) void k_tr(const float* __restrict__ tri,
                                            uint16_t* __restrict__ out) {
  __shared__ uint16_t tile[32 * 258];  // [c][x], stride 258 to break bank conflicts
  const int blk = blockIdx.x;          // 0..3071
  const int n = blk >> 8, y = blk & 255;
  const int t = threadIdx.x;
  for (int c = 0; c < 32; ++c) {
    float v = tri[((size_t)(n * 32 + c)) * 65536 + y * 256 + t];
    tile[c * 258 + t] = bf_rne(v);
  }
  __syncthreads();
  uint16_t* dst = out + ((size_t)(n * 256 + y)) * 256 * 32;
  const int c0 = (t & 7) * 4;
  for (int i = 0; i < 8; ++i) {
    int x = (t >> 3) + 32 * i;
    uint32 d0 = (uint32)tile[(c0 + 0) * 258 + x] | ((uint32)tile[(c0 + 1) * 258 + x] << 16);
    uint32 d1 = (uint32)tile[(c0 + 2) * 258 + x] | ((uint32)tile[(c0 + 3) * 258 + x] << 16);
    *(uint2*)(dst + x * 32 + c0) = make_uint2(d0, d1);
  }
}

// ---------- kernel 2: pack weights into MFMA A-frag layout + biases into C-layout ----------
// frag index bases per layer: {0,20,52,84,104,136,168}, Ks={5,8,8,5,8,8,8}, 176 frags total.
// frag(lay,mt,k): lane L holds W[mt*32+(L&31)][k*16+(L>>5)*8 + j], j=0..7 -> 16B
// packed-h column order: [feats 0..31 | freq 32..67 | pad 68..79]; w_in/w_skip cols permuted to match.
__global__ __launch_bounds__(256) void k_pack(
    const float* __restrict__ w_in, const float* __restrict__ w_skip,
    const float* __restrict__ w_before, const float* __restrict__ w_after,
    const float* __restrict__ w_out, const float* __restrict__ b_in,
    const float* __restrict__ b_skip, const float* __restrict__ b_before,
    const float* __restrict__ b_after, const float* __restrict__ b_out,
    uint16_t* __restrict__ wpack, float* __restrict__ bpack) {
  const int blk = blockIdx.x;
  if (blk >= 44) {  // bias pack: bpack[l*128 + mt*32 + half*16 + reg]
    for (int t = threadIdx.x; t < 800; t += 256) {
      int l, idx;
      if (t < 768) { l = t >> 7; idx = t & 127; }
      else { l = 6; idx = t - 768; }
      int mt = idx >> 5, rem = idx & 31;
      int half = rem >> 4, r = rem & 15;
      int f = mt * 32 + (r & 3) + 8 * (r >> 2) + 4 * half;
      float v;
      switch (l) {
        case 0: v = b_in[f]; break;
        case 1: v = b_before[f]; break;
        case 2: v = b_before[128 + f]; break;
        case 3: v = b_skip[f]; break;
        case 4: v = b_after[f]; break;
        case 5: v = b_after[128 + f]; break;
        default: v = (f < 4) ? b_out[f] : 0.0f; break;
      }
      bpack[l * 128 + idx] = v;
    }
    return;
  }
  const int w = blk * 4 + (threadIdx.x >> 6);  // 0..175
  const int L = threadIdx.x & 63;
  int lay, mt, k;
  if (w < 20)      { lay = 0; mt = w / 5;        k = w - mt * 5; }
  else if (w < 52) { int u = w - 20;  lay = 1; mt = u >> 3; k = u & 7; }
  else if (w < 84) { int u = w - 52;  lay = 2; mt = u >> 3; k = u & 7; }
  else if (w < 104){ int u = w - 84;  lay = 3; mt = u / 5;  k = u - mt * 5; }
  else if (w < 136){ int u = w - 104; lay = 4; mt = u >> 3; k = u & 7; }
  else if (w < 168){ int u = w - 136; lay = 5; mt = u >> 3; k = u & 7; }
  else             { lay = 6; mt = 0; k = w - 168; }
  const float* W;
  int insk = 0;
  switch (lay) {
    case 0: W = w_in; insk = 1; break;
    case 1: W = w_before; break;
    case 2: W = w_before + 16384; break;
    case 3: W = w_skip; insk = 1; break;
    case 4: W = w_after; break;
    case 5: W = w_after + 16384; break;
    default: W = w_out; break;
  }
  const int frow = mt * 32 + (L & 31);
  const int kbase = k * 16 + (L >> 5) * 8;
  uint16_t h[8];
#pragma unroll
  for (int j = 0; j < 8; ++j) {
    int kl = kbase + j;
    float v;
    if (insk) {
      int col = (kl < 32) ? (36 + kl) : ((kl < 68) ? (kl - 32) : -1);
      v = (col < 0) ? 0.0f : W[frow * 68 + col];
    } else if (lay == 6) {
      v = (frow < 4) ? W[frow * 128 + kl] : 0.0f;
    } else {
      v = W[frow * 128 + kl];
    }
    h[j] = bf_rne(v);
  }
  uint4 q;
  q.x = (uint32)h[0] | ((uint32)h[1] << 16);
  q.y = (uint32)h[2] | ((uint32)h[3] << 16);
  q.z = (uint32)h[4] | ((uint32)h[5] << 16);
  q.w = (uint32)h[6] | ((uint32)h[7] << 16);
  *(uint4*)(wpack + (size_t)w * 512 + L * 8) = q;
}

// ---------- kernel 3: fused gather + encode + MLP ----------
// LDS rows = points (64/block), 128 bf16 cols, 16B chunks XOR-swizzled by (row&15).
__global__ __launch_bounds__(256, 2) void k_main(
    const uint16_t* __restrict__ trit, const float* __restrict__ trif,
    const float* __restrict__ coords, const uint16_t* __restrict__ wpack,
    const float* __restrict__ bpack, float* __restrict__ dout, int fast) {
  __shared__ __align__(16) uint16_t h_s[64 * 128];
  __shared__ __align__(16) uint16_t a_s[64 * 128];
  const int t = threadIdx.x;

  // ---- phase 1: triplane gather + freq encode -> h ----
  {
    const int p = t >> 2, c = t & 3;
    const int pg = blockIdx.x * 64 + p;
    float cx = coords[pg * 3 + 0], cy = coords[pg * 3 + 1], cz = coords[pg * 3 + 2];
    // replicate reference fp exactly: scaled = fl(c+1)-1 ; norm = fl(c+1)*0.5
    float f1x = cx + 1.0f, f1y = cy + 1.0f, f1z = cz + 1.0f;
    float nx = f1x * 0.5f, ny = f1y * 0.5f, nz = f1z * 0.5f;
    float sx = f1x - 1.0f, sy = f1y - 1.0f, sz = f1z - 1.0f;
    bool sel = (nx > 0.f) & (nx < 1.f) & (ny > 0.f) & (ny < 1.f) & (nz > 0.f) & (nz < 1.f);
    const int b = pg >> 16;
    float acc[8];
#pragma unroll
    for (int j = 0; j < 8; ++j) acc[j] = 0.f;
#pragma unroll
    for (int pl = 0; pl < 3; ++pl) {
      float gx = (pl == 2) ? sy : sx;
      float gy = (pl == 0) ? sy : sz;
      float ix = ((gx + 1.0f) * 0.5f) * 255.0f;
      float iy = ((gy + 1.0f) * 0.5f) * 255.0f;
      float x0f = floorf(ix), y0f = floorf(iy);
      float wx = ix - x0f, wy = iy - y0f;
      float vx0 = (x0f >= 0.0f && x0f < 256.0f) ? 1.f : 0.f;
      float vx1 = (x0f >= -1.0f && x0f < 255.0f) ? 1.f : 0.f;
      float vy0 = (y0f >= 0.0f && y0f < 256.0f) ? 1.f : 0.f;
      float vy1 = (y0f >= -1.0f && y0f < 255.0f) ? 1.f : 0.f;
      int x0 = min(max((int)x0f, 0), 255), x1 = min(max((int)x0f + 1, 0), 255);
      int y0 = min(max((int)y0f, 0), 255), y1 = min(max((int)y0f + 1, 0), 255);
      float w00 = (1.f - wx) * (1.f - wy) * vx0 * vy0;
      float w10 = wx * (1.f - wy) * vx1 * vy0;
      float w01 = (1.f - wx) * wy * vx0 * vy1;
      float w11 = wx * wy * vx1 * vy1;
      const int n = 3 * b + pl;
      if (fast) {
        const uint16_t* base = trit + ((size_t)n << 21) + (c << 3);
        gacc(base + ((size_t)(y0 * 256 + x0) << 5), w00, acc);
        gacc(base + ((size_t)(y0 * 256 + x1) << 5), w10, acc);
        gacc(base + ((size_t)(y1 * 256 + x0) << 5), w01, acc);
        gacc(base + ((size_t)(y1 * 256 + x1) << 5), w11, acc);
      } else {
        const float* basef = trif + ((size_t)(n * 32 + c * 8) << 16);
#pragma unroll
        for (int jj = 0; jj < 8; ++jj) {
          const float* chp = basef + ((size_t)jj << 16);
          acc[jj] += w00 * chp[y0 * 256 + x0] + w10 * chp[y0 * 256 + x1] +
                     w01 * chp[y1 * 256 + x0] + w11 * chp[y1 * 256 + x1];
        }
      }
    }
    const int s = p & 15;
    uint16_t* hrow = h_s + p * 128;
    // feats -> cols [8c, 8c+8)
    *(uint4*)(hrow + (((c ^ s)) << 3)) =
        make_uint4(pack2(acc[0], acc[1]), pack2(acc[2], acc[3]),
                   pack2(acc[4], acc[5]), pack2(acc[6], acc[7]));
    if (c < 3) {
      // freq for dim c: cols 32+12c .. 32+12c+11 : [sin f0..f5, cos f0..f5]
      float nd = (c == 0) ? nx : (c == 1) ? ny : nz;
      float vals[12];
#pragma unroll
      for (int k = 0; k < 6; ++k) {
        float rev = nd * (0.5f * (float)(1 << k));  // angle / 2pi
        float r = rev - rintf(rev);
        vals[k] = __builtin_amdgcn_sinf(r);
        vals[6 + k] = __builtin_amdgcn_cosf(r);
      }
#pragma unroll
      for (int iw = 0; iw < 3; ++iw) {
        int byte = 64 + 24 * c + 8 * iw;
        int chunk = byte >> 4, off = byte & 15;
        *(uint2*)((char*)hrow + (((chunk ^ s)) << 4) + off) =
            make_uint2(pack2(vals[4 * iw + 0], vals[4 * iw + 1]),
                       pack2(vals[4 * iw + 2], vals[4 * iw + 3]));
      }
    } else {
      // zero pad cols 68..78, selector (0/1 bf16) at col 79
      *(uint2*)((char*)hrow + (((8 ^ s)) << 4) + 8) = make_uint2(0u, 0u);
      uint32 selw = sel ? 0x3F800000u : 0u;
      *(uint4*)((char*)hrow + (((9 ^ s)) << 4)) = make_uint4(0u, 0u, 0u, selw);
    }
  }
  __syncthreads();

  // ---- phase 2: MLP via mfma_f32_32x32x16_bf16, D = W * X^T ----
  const int w = t >> 6, L = t & 63;
  const int ih = w & 1, jh = w >> 1;   // feature-half, point-half
  const int kh = L >> 5;
  const int prow = jh * 32 + (L & 31); // this lane's point (B n-col & C col)
  const int ps = prow & 15;
  const uint16_t* hrow = h_s + prow * 128;
  uint16_t* arow = a_s + prow * 128;
  short8 bfr[8];
  const int FO[7] = {0, 20, 52, 84, 104, 136, 168};

#pragma unroll 1
  for (int l = 0; l < 6; ++l) {
    const bool fromH = (l == 0) || (l == 3);
    const uint16_t* src = fromH ? hrow : (const uint16_t*)arow;
    const int Ks = fromH ? 5 : 8;
    for (int k = 0; k < Ks; ++k)
      bfr[k] = *(const short8*)(src + (((2 * k + kh) ^ ps) << 3));
    if (!fromH) __syncthreads();  // all reads done before in-place writes
#pragma unroll 1
    for (int m = 0; m < 2; ++m) {
      const int mt = ih * 2 + m;
      const float4* bp = (const float4*)(bpack + l * 128 + mt * 32 + kh * 16);
      float4 b0 = bp[0], b1 = bp[1], b2 = bp[2], b3 = bp[3];
      floatx16 acc;
      acc[0] = b0.x; acc[1] = b0.y; acc[2] = b0.z; acc[3] = b0.w;
      acc[4] = b1.x; acc[5] = b1.y; acc[6] = b1.z; acc[7] = b1.w;
      acc[8] = b2.x; acc[9] = b2.y; acc[10] = b2.z; acc[11] = b2.w;
      acc[12] = b3.x; acc[13] = b3.y; acc[14] = b3.z; acc[15] = b3.w;
      const uint16_t* wp = wpack + (size_t)(FO[l] + mt * Ks) * 512 + L * 8;
      for (int k = 0; k < Ks; ++k) {
        short8 af = *(const short8*)(wp + k * 512);
        acc = __builtin_amdgcn_mfma_f32_32x32x16_bf16(af, bfr[k], acc, 0, 0, 0);
      }
#pragma unroll
      for (int g = 0; g < 4; ++g) {
        float v0 = fmaxf(acc[4 * g + 0], 0.f), v1 = fmaxf(acc[4 * g + 1], 0.f);
        float v2 = fmaxf(acc[4 * g + 2], 0.f), v3 = fmaxf(acc[4 * g + 3], 0.f);
        const int byte = 64 * mt + 16 * g + 8 * kh;
        uint16_t* dst =
            (uint16_t*)((char*)arow + ((((byte >> 4)) ^ ps) << 4) + (byte & 15));
        if (l == 3) {  // skip connection: x_old + relu(...)
          uint2 old = *(const uint2*)dst;
          v0 += __uint_as_float(old.x << 16);
          v1 += __uint_as_float(old.x & 0xFFFF0000u);
          v2 += __uint_as_float(old.y << 16);
          v3 += __uint_as_float(old.y & 0xFFFF0000u);
        }
        *(uint2*)dst = make_uint2(pack2(v0, v1), pack2(v2, v3));
      }
    }
    __syncthreads();
  }

  // ---- output layer (w_out padded to 32x128) + activations + store ----
  if (ih == 0) {
#pragma unroll
    for (int k = 0; k < 8; ++k)
      bfr[k] = *(const short8*)(arow + (((2 * k + kh) ^ ps) << 3));
    const float4* bp = (const float4*)(bpack + 768 + kh * 16);
    float4 b0 = bp[0], b1 = bp[1], b2 = bp[2], b3 = bp[3];
    floatx16 acc;
    acc[0] = b0.x; acc[1] = b0.y; acc[2] = b0.z; acc[3] = b0.w;
    acc[4] = b1.x; acc[5] = b1.y; acc[6] = b1.z; acc[7] = b1.w;
    acc[8] = b2.x; acc[9] = b2.y; acc[10] = b2.z; acc[11] = b2.w;
    acc[12] = b3.x; acc[13] = b3.y; acc[14] = b3.z; acc[15] = b3.w;
    const uint16_t* wp = wpack + (size_t)168 * 512 + L * 8;
#pragma unroll
    for (int k = 0; k < 8; ++k) {
      short8 af = *(const short8*)(wp + k * 512);
      acc = __builtin_amdgcn_mfma_f32_32x32x16_bf16(af, bfr[k], acc, 0, 0, 0);
    }
    if (kh == 0) {  // regs 0..3 = outputs 0..3 for point prow
      const int pg = blockIdx.x * 64 + prow;
      const float l2e = 1.44269504f;
      float r0 = 1.0f / (1.0f + exp2f(-l2e * acc[0]));
      float r1 = 1.0f / (1.0f + exp2f(-l2e * acc[1]));
      float r2 = 1.0f / (1.0f + exp2f(-l2e * acc[2]));
      uint16_t sv = hrow[(((9 ^ ps)) << 3) + 7];
      float dens = exp2f((acc[3] - 1.0f) * l2e) * (sv ? 1.0f : 0.0f);
      dout[pg * 3 + 0] = r0;
      dout[pg * 3 + 1] = r1;
      dout[pg * 3 + 2] = r2;
      dout[RGB_OFF + pg] = dens;
    }
  }
}

extern "C" void kernel_launch(void* const* d_in, const int* in_sizes, int n_in,
                              void* d_out, int out_size, void* d_ws, size_t ws_size,
                              hipStream_t stream) {
  const float* tri = (const float*)d_in[0];
  const float* coords = (const float*)d_in[1];
  const float* w_in = (const float*)d_in[2];
  const float* b_in = (const float*)d_in[3];
  const float* w_skip = (const float*)d_in[4];
  const float* b_skip = (const float*)d_in[5];
  const float* w_bef = (const float*)d_in[6];
  const float* b_bef = (const float*)d_in[7];
  const float* w_aft = (const float*)d_in[8];
  const float* b_aft = (const float*)d_in[9];
  const float* w_out = (const float*)d_in[10];
  const float* b_out = (const float*)d_in[11];
  const size_t TRI_B = (size_t)12 * 256 * 256 * 32 * 2;  // 50,331,648
  const size_t WP_B = (size_t)176 * 1024;                // 180,224
  const size_t BP_B = 3200;
  char* ws = (char*)d_ws;
  const int fast = (ws_size >= TRI_B + WP_B + BP_B) ? 1 : 0;
  uint16_t* trit;
  uint16_t* wpk;
  float* bpk;
  if (fast) {
    trit = (uint16_t*)ws;
    wpk = (uint16_t*)(ws + TRI_B);
    bpk = (float*)(ws + TRI_B + WP_B);
  } else {
    trit = (uint16_t*)ws;  // unused
    wpk = (uint16_t*)ws;
    bpk = (float*)(ws + WP_B);
  }
  if (fast) k_tr<<<dim3(3072), dim3(256), 0, stream>>>(tri, trit);
  k_pack<<<dim3(45), dim3(256), 0, stream>>>(w_in, w_skip, w_bef, w_aft, w_out,
                                             b_in, b_skip, b_bef, b_aft, b_out,
                                             wpk, bpk);
  k_main<<<dim3(4096), dim3(256), 0, stream>>>(trit, tri, coords, wpk, bpk,
                                               (float*)d_out, fast);
}

// Round 2
// 295.197 us; speedup vs baseline: 25.2132x; 25.2132x over previous
//
#include <hip/hip_runtime.h>
#include <stdint.h>

typedef short short8 __attribute__((ext_vector_type(8)));
typedef float floatx16 __attribute__((ext_vector_type(16)));
typedef unsigned int uint32;

#define NPTS (4 * 65536)
#define RGB_OFF (NPTS * 3)

// ---------- helpers ----------
__device__ __forceinline__ uint16_t bf_rne(float f) {
  uint32 u = __float_as_uint(f);
  u += 0x7FFFu + ((u >> 16) & 1u);
  return (uint16_t)(u >> 16);
}
// round-half-up bf16 pair pack (cheap: 1 add per value + merge)
__device__ __forceinline__ uint32 pack2(float a, float b) {
  uint32 ua = (__float_as_uint(a) + 0x8000u) >> 16;
  uint32 ub = (__float_as_uint(b) + 0x8000u) & 0xFFFF0000u;
  return ua | ub;
}
__device__ __forceinline__ void gacc(const uint16_t* p, float w, float* acc) {
  uint4 q = *(const uint4*)p;
  acc[0] += w * __uint_as_float(q.x << 16);
  acc[1] += w * __uint_as_float(q.x & 0xFFFF0000u);
  acc[2] += w * __uint_as_float(q.y << 16);
  acc[3] += w * __uint_as_float(q.y & 0xFFFF0000u);
  acc[4] += w * __uint_as_float(q.z << 16);
  acc[5] += w * __uint_as_float(q.z & 0xFFFF0000u);
  acc[6] += w * __uint_as_float(q.w << 16);
  acc[7] += w * __uint_as_float(q.w & 0xFFFF0000u);
}

// ---------- kernel 1: triplane (12,32,256,256) f32 -> (12,256,256,32) bf16 ----------
__global__ __launch_bounds__(256) void k_tr(const float* __restrict__ tri,
                                            uint16_t* __restrict__ out) {
  __shared__ uint16_t tile[32 * 258];  // [c][x], stride 258 to break bank conflicts
  const int blk = blockIdx.x;          // 0..3071
  const int n = blk >> 8, y = blk & 255;
  const int t = threadIdx.x;
  for (int c = 0; c < 32; ++c) {
    float v = tri[((size_t)(n * 32 + c)) * 65536 + y * 256 + t];
    tile[c * 258 + t] = bf_rne(v);
  }
  __syncthreads();
  uint16_t* dst = out + ((size_t)(n * 256 + y)) * 256 * 32;
  const int c0 = (t & 7) * 4;
  for (int i = 0; i < 8; ++i) {
    int x = (t >> 3) + 32 * i;
    uint32 d0 = (uint32)tile[(c0 + 0) * 258 + x] | ((uint32)tile[(c0 + 1) * 258 + x] << 16);
    uint32 d1 = (uint32)tile[(c0 + 2) * 258 + x] | ((uint32)tile[(c0 + 3) * 258 + x] << 16);
    *(uint2*)(dst + x * 32 + c0) = make_uint2(d0, d1);
  }
}

// ---------- kernel 2: pack weights into MFMA A-frag layout + biases into C-layout ----------
// frag index bases per layer: {0,20,52,84,104,136,168}, Ks={5,8,8,5,8,8,8}, 176 frags total.
// frag(lay,mt,k): lane L holds W[mt*32+(L&31)][k*16+(L>>5)*8 + j], j=0..7 -> 16B
// packed-h column order: [feats 0..31 | freq 32..67 | pad 68..79]; w_in/w_skip cols permuted to match.
__global__ __launch_bounds__(256) void k_pack(
    const float* __restrict__ w_in, const float* __restrict__ w_skip,
    const float* __restrict__ w_before, const float* __restrict__ w_after,
    const float* __restrict__ w_out, const float* __restrict__ b_in,
    const float* __restrict__ b_skip, const float* __restrict__ b_before,
    const float* __restrict__ b_after, const float* __restrict__ b_out,
    uint16_t* __restrict__ wpack, float* __restrict__ bpack) {
  const int blk = blockIdx.x;
  if (blk >= 44) {  // bias pack: bpack[l*128 + mt*32 + half*16 + reg]
    for (int t = threadIdx.x; t < 800; t += 256) {
      int l, idx;
      if (t < 768) { l = t >> 7; idx = t & 127; }
      else { l = 6; idx = t - 768; }
      int mt = idx >> 5, rem = idx & 31;
      int half = rem >> 4, r = rem & 15;
      int f = mt * 32 + (r & 3) + 8 * (r >> 2) + 4 * half;
      float v;
      switch (l) {
        case 0: v = b_in[f]; break;
        case 1: v = b_before[f]; break;
        case 2: v = b_before[128 + f]; break;
        case 3: v = b_skip[f]; break;
        case 4: v = b_after[f]; break;
        case 5: v = b_after[128 + f]; break;
        default: v = (f < 4) ? b_out[f] : 0.0f; break;
      }
      bpack[l * 128 + idx] = v;
    }
    return;
  }
  const int w = blk * 4 + (threadIdx.x >> 6);  // 0..175
  const int L = threadIdx.x & 63;
  int lay, mt, k;
  if (w < 20)      { lay = 0; mt = w / 5;        k = w - mt * 5; }
  else if (w < 52) { int u = w - 20;  lay = 1; mt = u >> 3; k = u & 7; }
  else if (w < 84) { int u = w - 52;  lay = 2; mt = u >> 3; k = u & 7; }
  else if (w < 104){ int u = w - 84;  lay = 3; mt = u / 5;  k = u - mt * 5; }
  else if (w < 136){ int u = w - 104; lay = 4; mt = u >> 3; k = u & 7; }
  else if (w < 168){ int u = w - 136; lay = 5; mt = u >> 3; k = u & 7; }
  else             { lay = 6; mt = 0; k = w - 168; }
  const float* W;
  int insk = 0;
  switch (lay) {
    case 0: W = w_in; insk = 1; break;
    case 1: W = w_before; break;
    case 2: W = w_before + 16384; break;
    case 3: W = w_skip; insk = 1; break;
    case 4: W = w_after; break;
    case 5: W = w_after + 16384; break;
    default: W = w_out; break;
  }
  const int frow = mt * 32 + (L & 31);
  const int kbase = k * 16 + (L >> 5) * 8;
  uint16_t h[8];
#pragma unroll
  for (int j = 0; j < 8; ++j) {
    int kl = kbase + j;
    float v;
    if (insk) {
      int col = (kl < 32) ? (36 + kl) : ((kl < 68) ? (kl - 32) : -1);
      v = (col < 0) ? 0.0f : W[frow * 68 + col];
    } else if (lay == 6) {
      v = (frow < 4) ? W[frow * 128 + kl] : 0.0f;
    } else {
      v = W[frow * 128 + kl];
    }
    h[j] = bf_rne(v);
  }
  uint4 q;
  q.x = (uint32)h[0] | ((uint32)h[1] << 16);
  q.y = (uint32)h[2] | ((uint32)h[3] << 16);
  q.z = (uint32)h[4] | ((uint32)h[5] << 16);
  q.w = (uint32)h[6] | ((uint32)h[7] << 16);
  *(uint4*)(wpack + (size_t)w * 512 + L * 8) = q;
}

// ---------- MLP layer, fully compile-time (no dynamic-indexed arrays!) ----------
// LAY: bias row; Ks: #k-frags (5 for 80-col input, 8 for 128); FOFF: frag base;
// FROMH: read B from h_s; SKIP: epilogue adds old activation (skip connection).
template <int LAY, int Ks, int FOFF, bool FROMH, bool SKIP>
__device__ __forceinline__ void mlp_layer(const uint16_t* __restrict__ hrow,
                                          uint16_t* __restrict__ arow,
                                          const uint16_t* __restrict__ wpack,
                                          const float* __restrict__ bpack,
                                          int ih, int kh, int L, int ps) {
  const uint16_t* src = FROMH ? hrow : (const uint16_t*)arow;
  short8 bfr[Ks];
#pragma unroll
  for (int k = 0; k < Ks; ++k)
    bfr[k] = *(const short8*)(src + (((2 * k + kh) ^ ps) << 3));
  if (!FROMH) __syncthreads();  // all reads done before in-place writes
#pragma unroll
  for (int m = 0; m < 2; ++m) {
    const int mt = ih * 2 + m;
    const float4* bp = (const float4*)(bpack + LAY * 128 + mt * 32 + kh * 16);
    float4 b0 = bp[0], b1 = bp[1], b2 = bp[2], b3 = bp[3];
    floatx16 acc;
    acc[0] = b0.x; acc[1] = b0.y; acc[2] = b0.z; acc[3] = b0.w;
    acc[4] = b1.x; acc[5] = b1.y; acc[6] = b1.z; acc[7] = b1.w;
    acc[8] = b2.x; acc[9] = b2.y; acc[10] = b2.z; acc[11] = b2.w;
    acc[12] = b3.x; acc[13] = b3.y; acc[14] = b3.z; acc[15] = b3.w;
    const uint16_t* wp = wpack + (size_t)(FOFF + mt * Ks) * 512 + L * 8;
#pragma unroll
    for (int k = 0; k < Ks; ++k) {
      short8 af = *(const short8*)(wp + k * 512);
      acc = __builtin_amdgcn_mfma_f32_32x32x16_bf16(af, bfr[k], acc, 0, 0, 0);
    }
#pragma unroll
    for (int g = 0; g < 4; ++g) {
      float v0 = fmaxf(acc[4 * g + 0], 0.f), v1 = fmaxf(acc[4 * g + 1], 0.f);
      float v2 = fmaxf(acc[4 * g + 2], 0.f), v3 = fmaxf(acc[4 * g + 3], 0.f);
      const int byte = 64 * mt + 16 * g + 8 * kh;
      uint16_t* dst =
          (uint16_t*)((char*)arow + ((((byte >> 4)) ^ ps) << 4) + (byte & 15));
      if (SKIP) {  // skip connection: x_old + relu(...)
        uint2 old = *(const uint2*)dst;
        v0 += __uint_as_float(old.x << 16);
        v1 += __uint_as_float(old.x & 0xFFFF0000u);
        v2 += __uint_as_float(old.y << 16);
        v3 += __uint_as_float(old.y & 0xFFFF0000u);
      }
      *(uint2*)dst = make_uint2(pack2(v0, v1), pack2(v2, v3));
    }
  }
  __syncthreads();
}

// ---------- kernel 3: fused gather + encode + MLP ----------
// LDS rows = points (64/block), 128 bf16 cols, 16B chunks XOR-swizzled by (row&15).
__global__ __launch_bounds__(256, 2) void k_main(
    const uint16_t* __restrict__ trit, const float* __restrict__ trif,
    const float* __restrict__ coords, const uint16_t* __restrict__ wpack,
    const float* __restrict__ bpack, float* __restrict__ dout, int fast) {
  __shared__ __align__(16) uint16_t h_s[64 * 128];
  __shared__ __align__(16) uint16_t a_s[64 * 128];
  const int t = threadIdx.x;

  // ---- phase 1: triplane gather + freq encode -> h ----
  {
    const int p = t >> 2, c = t & 3;
    const int pg = blockIdx.x * 64 + p;
    float cx = coords[pg * 3 + 0], cy = coords[pg * 3 + 1], cz = coords[pg * 3 + 2];
    // replicate reference fp exactly: scaled = fl(c+1)-1 ; norm = fl(c+1)*0.5
    float f1x = cx + 1.0f, f1y = cy + 1.0f, f1z = cz + 1.0f;
    float nx = f1x * 0.5f, ny = f1y * 0.5f, nz = f1z * 0.5f;
    float sx = f1x - 1.0f, sy = f1y - 1.0f, sz = f1z - 1.0f;
    bool sel = (nx > 0.f) & (nx < 1.f) & (ny > 0.f) & (ny < 1.f) & (nz > 0.f) & (nz < 1.f);
    const int b = pg >> 16;
    float acc[8];
#pragma unroll
    for (int j = 0; j < 8; ++j) acc[j] = 0.f;
#pragma unroll
    for (int pl = 0; pl < 3; ++pl) {
      float gx = (pl == 2) ? sy : sx;
      float gy = (pl == 0) ? sy : sz;
      float ix = ((gx + 1.0f) * 0.5f) * 255.0f;
      float iy = ((gy + 1.0f) * 0.5f) * 255.0f;
      float x0f = floorf(ix), y0f = floorf(iy);
      float wx = ix - x0f, wy = iy - y0f;
      float vx0 = (x0f >= 0.0f && x0f < 256.0f) ? 1.f : 0.f;
      float vx1 = (x0f >= -1.0f && x0f < 255.0f) ? 1.f : 0.f;
      float vy0 = (y0f >= 0.0f && y0f < 256.0f) ? 1.f : 0.f;
      float vy1 = (y0f >= -1.0f && y0f < 255.0f) ? 1.f : 0.f;
      int x0 = min(max((int)x0f, 0), 255), x1 = min(max((int)x0f + 1, 0), 255);
      int y0 = min(max((int)y0f, 0), 255), y1 = min(max((int)y0f + 1, 0), 255);
      float w00 = (1.f - wx) * (1.f - wy) * vx0 * vy0;
      float w10 = wx * (1.f - wy) * vx1 * vy0;
      float w01 = (1.f - wx) * wy * vx0 * vy1;
      float w11 = wx * wy * vx1 * vy1;
      const int n = 3 * b + pl;
      if (fast) {
        const uint16_t* base = trit + ((size_t)n << 21) + (c << 3);
        gacc(base + ((size_t)(y0 * 256 + x0) << 5), w00, acc);
        gacc(base + ((size_t)(y0 * 256 + x1) << 5), w10, acc);
        gacc(base + ((size_t)(y1 * 256 + x0) << 5), w01, acc);
        gacc(base + ((size_t)(y1 * 256 + x1) << 5), w11, acc);
      } else {
        const float* basef = trif + ((size_t)(n * 32 + c * 8) << 16);
#pragma unroll
        for (int jj = 0; jj < 8; ++jj) {
          const float* chp = basef + ((size_t)jj << 16);
          acc[jj] += w00 * chp[y0 * 256 + x0] + w10 * chp[y0 * 256 + x1] +
                     w01 * chp[y1 * 256 + x0] + w11 * chp[y1 * 256 + x1];
        }
      }
    }
    const int s = p & 15;
    uint16_t* hrow = h_s + p * 128;
    // feats -> cols [8c, 8c+8)
    *(uint4*)(hrow + (((c ^ s)) << 3)) =
        make_uint4(pack2(acc[0], acc[1]), pack2(acc[2], acc[3]),
                   pack2(acc[4], acc[5]), pack2(acc[6], acc[7]));
    if (c < 3) {
      // freq for dim c: cols 32+12c .. 32+12c+11 : [sin f0..f5, cos f0..f5]
      float nd = (c == 0) ? nx : (c == 1) ? ny : nz;
      float vals[12];
#pragma unroll
      for (int k = 0; k < 6; ++k) {
        float rev = nd * (0.5f * (float)(1 << k));  // angle / 2pi
        float r = rev - rintf(rev);
        vals[k] = __builtin_amdgcn_sinf(r);
        vals[6 + k] = __builtin_amdgcn_cosf(r);
      }
#pragma unroll
      for (int iw = 0; iw < 3; ++iw) {
        int byte = 64 + 24 * c + 8 * iw;
        int chunk = byte >> 4, off = byte & 15;
        *(uint2*)((char*)hrow + (((chunk ^ s)) << 4) + off) =
            make_uint2(pack2(vals[4 * iw + 0], vals[4 * iw + 1]),
                       pack2(vals[4 * iw + 2], vals[4 * iw + 3]));
      }
    } else {
      // zero pad cols 68..78, selector (0/1 bf16) at col 79
      *(uint2*)((char*)hrow + (((8 ^ s)) << 4) + 8) = make_uint2(0u, 0u);
      uint32 selw = sel ? 0x3F800000u : 0u;
      *(uint4*)((char*)hrow + (((9 ^ s)) << 4)) = make_uint4(0u, 0u, 0u, selw);
    }
  }
  __syncthreads();

  // ---- phase 2: MLP via mfma_f32_32x32x16_bf16, D = W * X^T ----
  const int w = t >> 6, L = t & 63;
  const int ih = w & 1, jh = w >> 1;   // feature-half, point-half
  const int kh = L >> 5;
  const int prow = jh * 32 + (L & 31); // this lane's point (B n-col & C col)
  const int ps = prow & 15;
  const uint16_t* hrow = h_s + prow * 128;
  uint16_t* arow = a_s + prow * 128;

  mlp_layer<0, 5, 0,   true,  false>(hrow, arow, wpack, bpack, ih, kh, L, ps);
  mlp_layer<1, 8, 20,  false, false>(hrow, arow, wpack, bpack, ih, kh, L, ps);
  mlp_layer<2, 8, 52,  false, false>(hrow, arow, wpack, bpack, ih, kh, L, ps);
  mlp_layer<3, 5, 84,  true,  true >(hrow, arow, wpack, bpack, ih, kh, L, ps);
  mlp_layer<4, 8, 104, false, false>(hrow, arow, wpack, bpack, ih, kh, L, ps);
  mlp_layer<5, 8, 136, false, false>(hrow, arow, wpack, bpack, ih, kh, L, ps);

  // ---- output layer (w_out padded to 32x128) + activations + store ----
  if (ih == 0) {
    short8 bfr[8];
#pragma unroll
    for (int k = 0; k < 8; ++k)
      bfr[k] = *(const short8*)(arow + (((2 * k + kh) ^ ps) << 3));
    const float4* bp = (const float4*)(bpack + 768 + kh * 16);
    float4 b0 = bp[0], b1 = bp[1], b2 = bp[2], b3 = bp[3];
    floatx16 acc;
    acc[0] = b0.x; acc[1] = b0.y; acc[2] = b0.z; acc[3] = b0.w;
    acc[4] = b1.x; acc[5] = b1.y; acc[6] = b1.z; acc[7] = b1.w;
    acc[8] = b2.x; acc[9] = b2.y; acc[10] = b2.z; acc[11] = b2.w;
    acc[12] = b3.x; acc[13] = b3.y; acc[14] = b3.z; acc[15] = b3.w;
    const uint16_t* wp = wpack + (size_t)168 * 512 + L * 8;
#pragma unroll
    for (int k = 0; k < 8; ++k) {
      short8 af = *(const short8*)(wp + k * 512);
      acc = __builtin_amdgcn_mfma_f32_32x32x16_bf16(af, bfr[k], acc, 0, 0, 0);
    }
    if (kh == 0) {  // regs 0..3 = outputs 0..3 for point prow
      const int pg = blockIdx.x * 64 + prow;
      const float l2e = 1.44269504f;
      float r0 = 1.0f / (1.0f + exp2f(-l2e * acc[0]));
      float r1 = 1.0f / (1.0f + exp2f(-l2e * acc[1]));
      float r2 = 1.0f / (1.0f + exp2f(-l2e * acc[2]));
      uint16_t sv = hrow[(((9 ^ ps)) << 3) + 7];
      float dens = exp2f((acc[3] - 1.0f) * l2e) * (sv ? 1.0f : 0.0f);
      dout[pg * 3 + 0] = r0;
      dout[pg * 3 + 1] = r1;
      dout[pg * 3 + 2] = r2;
      dout[RGB_OFF + pg] = dens;
    }
  }
}

extern "C" void kernel_launch(void* const* d_in, const int* in_sizes, int n_in,
                              void* d_out, int out_size, void* d_ws, size_t ws_size,
                              hipStream_t stream) {
  const float* tri = (const float*)d_in[0];
  const float* coords = (const float*)d_in[1];
  const float* w_in = (const float*)d_in[2];
  const float* b_in = (const float*)d_in[3];
  const float* w_skip = (const float*)d_in[4];
  const float* b_skip = (const float*)d_in[5];
  const float* w_bef = (const float*)d_in[6];
  const float* b_bef = (const float*)d_in[7];
  const float* w_aft = (const float*)d_in[8];
  const float* b_aft = (const float*)d_in[9];
  const float* w_out = (const float*)d_in[10];
  const float* b_out = (const float*)d_in[11];
  const size_t TRI_B = (size_t)12 * 256 * 256 * 32 * 2;  // 50,331,648
  const size_t WP_B = (size_t)176 * 1024;                // 180,224
  const size_t BP_B = 3200;
  char* ws = (char*)d_ws;
  const int fast = (ws_size >= TRI_B + WP_B + BP_B) ? 1 : 0;
  uint16_t* trit;
  uint16_t* wpk;
  float* bpk;
  if (fast) {
    trit = (uint16_t*)ws;
    wpk = (uint16_t*)(ws + TRI_B);
    bpk = (float*)(ws + TRI_B + WP_B);
  } else {
    trit = (uint16_t*)ws;  // unused
    wpk = (uint16_t*)ws;
    bpk = (float*)(ws + WP_B);
  }
  if (fast) k_tr<<<dim3(3072), dim3(256), 0, stream>>>(tri, trit);
  k_pack<<<dim3(45), dim3(256), 0, stream>>>(w_in, w_skip, w_bef, w_aft, w_out,
                                             b_in, b_skip, b_bef, b_aft, b_out,
                                             wpk, bpk);
  k_main<<<dim3(4096), dim3(256), 0, stream>>>(trit, tri, coords, wpk, bpk,
                                               (float*)d_out, fast);
}

// Round 3
// 278.354 us; speedup vs baseline: 26.7388x; 1.0605x over previous
//
#include <hip/hip_runtime.h>
#include <stdint.h>

typedef short short8 __attribute__((ext_vector_type(8)));
typedef float floatx16 __attribute__((ext_vector_type(16)));
typedef unsigned int uint32;

#define NPTS (4 * 65536)
#define RGB_OFF (NPTS * 3)

// ---------- helpers ----------
__device__ __forceinline__ uint16_t bf_rne(float f) {
  uint32 u = __float_as_uint(f);
  u += 0x7FFFu + ((u >> 16) & 1u);
  return (uint16_t)(u >> 16);
}
// pack two f32 -> two bf16 (round-half-up) via v_perm_b32: 3 VALU ops
__device__ __forceinline__ uint32 pack2(float a, float b) {
  return __builtin_amdgcn_perm(__float_as_uint(b) + 0x8000u,
                               __float_as_uint(a) + 0x8000u, 0x07060302u);
}
__device__ __forceinline__ void gacc(const uint16_t* p, float w, float* acc) {
  uint4 q = *(const uint4*)p;
  acc[0] += w * __uint_as_float(q.x << 16);
  acc[1] += w * __uint_as_float(q.x & 0xFFFF0000u);
  acc[2] += w * __uint_as_float(q.y << 16);
  acc[3] += w * __uint_as_float(q.y & 0xFFFF0000u);
  acc[4] += w * __uint_as_float(q.z << 16);
  acc[5] += w * __uint_as_float(q.z & 0xFFFF0000u);
  acc[6] += w * __uint_as_float(q.w << 16);
  acc[7] += w * __uint_as_float(q.w & 0xFFFF0000u);
}

// ---------- kernel 1: triplane (12,32,256,256) f32 -> (12,256,256,32) bf16 ----------
__global__ __launch_bounds__(256) void k_tr(const float* __restrict__ tri,
                                            uint16_t* __restrict__ out) {
  __shared__ uint16_t tile[32 * 258];
  const int blk = blockIdx.x;  // 0..3071
  const int n = blk >> 8, y = blk & 255;
  const int t = threadIdx.x;
  for (int c = 0; c < 32; ++c) {
    float v = tri[((size_t)(n * 32 + c)) * 65536 + y * 256 + t];
    tile[c * 258 + t] = bf_rne(v);
  }
  __syncthreads();
  uint16_t* dst = out + ((size_t)(n * 256 + y)) * 256 * 32;
  const int c0 = (t & 7) * 4;
  for (int i = 0; i < 8; ++i) {
    int x = (t >> 3) + 32 * i;
    uint32 d0 = (uint32)tile[(c0 + 0) * 258 + x] | ((uint32)tile[(c0 + 1) * 258 + x] << 16);
    uint32 d1 = (uint32)tile[(c0 + 2) * 258 + x] | ((uint32)tile[(c0 + 3) * 258 + x] << 16);
    *(uint2*)(dst + x * 32 + c0) = make_uint2(d0, d1);
  }
}

// ---------- kernel 2: pack weights into MFMA A-frag layout + biases into C-layout ----------
__global__ __launch_bounds__(256) void k_pack(
    const float* __restrict__ w_in, const float* __restrict__ w_skip,
    const float* __restrict__ w_before, const float* __restrict__ w_after,
    const float* __restrict__ w_out, const float* __restrict__ b_in,
    const float* __restrict__ b_skip, const float* __restrict__ b_before,
    const float* __restrict__ b_after, const float* __restrict__ b_out,
    uint16_t* __restrict__ wpack, float* __restrict__ bpack) {
  const int blk = blockIdx.x;
  if (blk >= 44) {  // bias pack: bpack[l*128 + mt*32 + half*16 + reg]
    for (int t = threadIdx.x; t < 800; t += 256) {
      int l, idx;
      if (t < 768) { l = t >> 7; idx = t & 127; }
      else { l = 6; idx = t - 768; }
      int mt = idx >> 5, rem = idx & 31;
      int half = rem >> 4, r = rem & 15;
      int f = mt * 32 + (r & 3) + 8 * (r >> 2) + 4 * half;
      float v;
      switch (l) {
        case 0: v = b_in[f]; break;
        case 1: v = b_before[f]; break;
        case 2: v = b_before[128 + f]; break;
        case 3: v = b_skip[f]; break;
        case 4: v = b_after[f]; break;
        case 5: v = b_after[128 + f]; break;
        default: v = (f < 4) ? b_out[f] : 0.0f; break;
      }
      bpack[l * 128 + idx] = v;
    }
    return;
  }
  const int w = blk * 4 + (threadIdx.x >> 6);  // 0..175
  const int L = threadIdx.x & 63;
  int lay, mt, k;
  if (w < 20)      { lay = 0; mt = w / 5;        k = w - mt * 5; }
  else if (w < 52) { int u = w - 20;  lay = 1; mt = u >> 3; k = u & 7; }
  else if (w < 84) { int u = w - 52;  lay = 2; mt = u >> 3; k = u & 7; }
  else if (w < 104){ int u = w - 84;  lay = 3; mt = u / 5;  k = u - mt * 5; }
  else if (w < 136){ int u = w - 104; lay = 4; mt = u >> 3; k = u & 7; }
  else if (w < 168){ int u = w - 136; lay = 5; mt = u >> 3; k = u & 7; }
  else             { lay = 6; mt = 0; k = w - 168; }
  const float* W;
  int insk = 0;
  switch (lay) {
    case 0: W = w_in; insk = 1; break;
    case 1: W = w_before; break;
    case 2: W = w_before + 16384; break;
    case 3: W = w_skip; insk = 1; break;
    case 4: W = w_after; break;
    case 5: W = w_after + 16384; break;
    default: W = w_out; break;
  }
  const int frow = mt * 32 + (L & 31);
  const int kbase = k * 16 + (L >> 5) * 8;
  uint16_t h[8];
#pragma unroll
  for (int j = 0; j < 8; ++j) {
    int kl = kbase + j;
    float v;
    if (insk) {
      int col = (kl < 32) ? (36 + kl) : ((kl < 68) ? (kl - 32) : -1);
      v = (col < 0) ? 0.0f : W[frow * 68 + col];
    } else if (lay == 6) {
      v = (frow < 4) ? W[frow * 128 + kl] : 0.0f;
    } else {
      v = W[frow * 128 + kl];
    }
    h[j] = bf_rne(v);
  }
  uint4 q;
  q.x = (uint32)h[0] | ((uint32)h[1] << 16);
  q.y = (uint32)h[2] | ((uint32)h[3] << 16);
  q.z = (uint32)h[4] | ((uint32)h[5] << 16);
  q.w = (uint32)h[6] | ((uint32)h[7] << 16);
  *(uint4*)(wpack + (size_t)w * 512 + L * 8) = q;
}

// ---------- MLP layer, 2x2 register-blocked (2 mt x 2 jh per wave) ----------
template <int LAY, int Ks, int FOFF, bool FROMH, bool SKIP>
__device__ __forceinline__ void mlp_layer(
    const uint16_t* __restrict__ hrow0, const uint16_t* __restrict__ hrow1,
    uint16_t* __restrict__ arow0, uint16_t* __restrict__ arow1,
    const uint16_t* __restrict__ wpack, const float* __restrict__ bpack,
    int mt0, int kh, int L, int ps) {
  const uint16_t* src0 = FROMH ? hrow0 : (const uint16_t*)arow0;
  const uint16_t* src1 = FROMH ? hrow1 : (const uint16_t*)arow1;
  short8 b0[Ks], b1[Ks];
#pragma unroll
  for (int k = 0; k < Ks; ++k) {
    b0[k] = *(const short8*)(src0 + (((2 * k + kh) ^ ps) << 3));
    b1[k] = *(const short8*)(src1 + (((2 * k + kh) ^ ps) << 3));
  }
  if (!FROMH) __syncthreads();  // all reads done before in-place writes
  // bias init: 4 accs (2 mt x 2 jh); same bias for both jh of an mt
  floatx16 a00, a01, a10, a11;
  {
    const float4* bp0 = (const float4*)(bpack + LAY * 128 + mt0 * 32 + kh * 16);
    const float4* bp1 = (const float4*)(bpack + LAY * 128 + (mt0 + 1) * 32 + kh * 16);
#pragma unroll
    for (int g = 0; g < 4; ++g) {
      float4 v0 = bp0[g], v1 = bp1[g];
      a00[4 * g + 0] = v0.x; a00[4 * g + 1] = v0.y; a00[4 * g + 2] = v0.z; a00[4 * g + 3] = v0.w;
      a10[4 * g + 0] = v1.x; a10[4 * g + 1] = v1.y; a10[4 * g + 2] = v1.z; a10[4 * g + 3] = v1.w;
    }
    a01 = a00; a11 = a10;
  }
  const uint16_t* wp0 = wpack + (size_t)(FOFF + mt0 * Ks) * 512 + L * 8;
  const uint16_t* wp1 = wp0 + (size_t)Ks * 512;
#pragma unroll
  for (int k = 0; k < Ks; ++k) {
    short8 af0 = *(const short8*)(wp0 + k * 512);
    short8 af1 = *(const short8*)(wp1 + k * 512);
    a00 = __builtin_amdgcn_mfma_f32_32x32x16_bf16(af0, b0[k], a00, 0, 0, 0);
    a01 = __builtin_amdgcn_mfma_f32_32x32x16_bf16(af0, b1[k], a01, 0, 0, 0);
    a10 = __builtin_amdgcn_mfma_f32_32x32x16_bf16(af1, b0[k], a10, 0, 0, 0);
    a11 = __builtin_amdgcn_mfma_f32_32x32x16_bf16(af1, b1[k], a11, 0, 0, 0);
  }
  // epilogue: relu (+skip) -> bf16 -> LDS
#pragma unroll
  for (int mi = 0; mi < 2; ++mi) {
    const int mt = mt0 + mi;
#pragma unroll
    for (int j = 0; j < 2; ++j) {
      uint16_t* arow = j ? arow1 : arow0;
      const floatx16& ac = mi ? (j ? a11 : a10) : (j ? a01 : a00);
#pragma unroll
      for (int g = 0; g < 4; ++g) {
        float v0 = fmaxf(ac[4 * g + 0], 0.f), v1 = fmaxf(ac[4 * g + 1], 0.f);
        float v2 = fmaxf(ac[4 * g + 2], 0.f), v3 = fmaxf(ac[4 * g + 3], 0.f);
        const int byte = 64 * mt + 16 * g + 8 * kh;
        uint16_t* dst =
            (uint16_t*)((char*)arow + ((((byte >> 4)) ^ ps) << 4) + (byte & 15));
        if (SKIP) {
          uint2 old = *(const uint2*)dst;
          v0 += __uint_as_float(old.x << 16);
          v1 += __uint_as_float(old.x & 0xFFFF0000u);
          v2 += __uint_as_float(old.y << 16);
          v3 += __uint_as_float(old.y & 0xFFFF0000u);
        }
        *(uint2*)dst = make_uint2(pack2(v0, v1), pack2(v2, v3));
      }
    }
  }
  __syncthreads();
}

// ---------- kernel 3: fused gather + encode + MLP (128 pts/block, 4 waves) ----------
__global__ __launch_bounds__(256, 2) void k_main(
    const uint16_t* __restrict__ trit, const float* __restrict__ trif,
    const float* __restrict__ coords, const uint16_t* __restrict__ wpack,
    const float* __restrict__ bpack, float* __restrict__ dout, int fast) {
  __shared__ __align__(16) uint16_t h_s[128 * 128];
  __shared__ __align__(16) uint16_t a_s[128 * 128];
  const int t = threadIdx.x;

  // ---- phase 1: triplane gather + freq encode -> h (2 threads/pt, 16 ch each) ----
  {
    const int p = t >> 1, c = t & 1;
    const int pg = blockIdx.x * 128 + p;
    float cx = coords[pg * 3 + 0], cy = coords[pg * 3 + 1], cz = coords[pg * 3 + 2];
    float f1x = cx + 1.0f, f1y = cy + 1.0f, f1z = cz + 1.0f;
    float nx = f1x * 0.5f, ny = f1y * 0.5f, nz = f1z * 0.5f;
    float sx = f1x - 1.0f, sy = f1y - 1.0f, sz = f1z - 1.0f;
    bool sel = (nx > 0.f) & (nx < 1.f) & (ny > 0.f) & (ny < 1.f) & (nz > 0.f) & (nz < 1.f);
    const int b = pg >> 16;
    float acc[16];
#pragma unroll
    for (int j = 0; j < 16; ++j) acc[j] = 0.f;
#pragma unroll
    for (int pl = 0; pl < 3; ++pl) {
      float gx = (pl == 2) ? sy : sx;
      float gy = (pl == 0) ? sy : sz;
      float ix = ((gx + 1.0f) * 0.5f) * 255.0f;
      float iy = ((gy + 1.0f) * 0.5f) * 255.0f;
      float x0f = floorf(ix), y0f = floorf(iy);
      float wx = ix - x0f, wy = iy - y0f;
      float vx0 = (x0f >= 0.0f && x0f < 256.0f) ? 1.f : 0.f;
      float vx1 = (x0f >= -1.0f && x0f < 255.0f) ? 1.f : 0.f;
      float vy0 = (y0f >= 0.0f && y0f < 256.0f) ? 1.f : 0.f;
      float vy1 = (y0f >= -1.0f && y0f < 255.0f) ? 1.f : 0.f;
      int x0 = min(max((int)x0f, 0), 255), x1 = min(max((int)x0f + 1, 0), 255);
      int y0 = min(max((int)y0f, 0), 255), y1 = min(max((int)y0f + 1, 0), 255);
      float w00 = (1.f - wx) * (1.f - wy) * vx0 * vy0;
      float w10 = wx * (1.f - wy) * vx1 * vy0;
      float w01 = (1.f - wx) * wy * vx0 * vy1;
      float w11 = wx * wy * vx1 * vy1;
      const int n = 3 * b + pl;
      if (fast) {
        const uint16_t* base = trit + ((size_t)n << 21) + (c << 4);
        const uint16_t* p00 = base + ((size_t)(y0 * 256 + x0) << 5);
        const uint16_t* p10 = base + ((size_t)(y0 * 256 + x1) << 5);
        const uint16_t* p01 = base + ((size_t)(y1 * 256 + x0) << 5);
        const uint16_t* p11 = base + ((size_t)(y1 * 256 + x1) << 5);
        gacc(p00, w00, acc); gacc(p00 + 8, w00, acc + 8);
        gacc(p10, w10, acc); gacc(p10 + 8, w10, acc + 8);
        gacc(p01, w01, acc); gacc(p01 + 8, w01, acc + 8);
        gacc(p11, w11, acc); gacc(p11 + 8, w11, acc + 8);
      } else {
        const float* basef = trif + ((size_t)(n * 32 + c * 16) << 16);
#pragma unroll
        for (int jj = 0; jj < 16; ++jj) {
          const float* chp = basef + ((size_t)jj << 16);
          acc[jj] += w00 * chp[y0 * 256 + x0] + w10 * chp[y0 * 256 + x1] +
                     w01 * chp[y1 * 256 + x0] + w11 * chp[y1 * 256 + x1];
        }
      }
    }
    const int s = p & 15;
    uint16_t* hrow = h_s + p * 128;
    // feats: 16 channels -> chunks 2c, 2c+1
    *(uint4*)(hrow + (((2 * c + 0) ^ s) << 3)) =
        make_uint4(pack2(acc[0], acc[1]), pack2(acc[2], acc[3]),
                   pack2(acc[4], acc[5]), pack2(acc[6], acc[7]));
    *(uint4*)(hrow + (((2 * c + 1) ^ s) << 3)) =
        make_uint4(pack2(acc[8], acc[9]), pack2(acc[10], acc[11]),
                   pack2(acc[12], acc[13]), pack2(acc[14], acc[15]));
    if (c == 0) {
      // dims x,y -> cols 32..55 (chunks 4,5,6): [sx0..5,cx0..5, sy0..5,cy0..5]
      float v[24];
#pragma unroll
      for (int d = 0; d < 2; ++d) {
        float nd = d ? ny : nx;
#pragma unroll
        for (int k = 0; k < 6; ++k) {
          float rev = nd * (0.5f * (float)(1 << k));
          float r = rev - rintf(rev);
          v[12 * d + k] = __builtin_amdgcn_sinf(r);
          v[12 * d + 6 + k] = __builtin_amdgcn_cosf(r);
        }
      }
      *(uint4*)(hrow + ((4 ^ s) << 3)) =
          make_uint4(pack2(v[0], v[1]), pack2(v[2], v[3]), pack2(v[4], v[5]), pack2(v[6], v[7]));
      *(uint4*)(hrow + ((5 ^ s) << 3)) =
          make_uint4(pack2(v[8], v[9]), pack2(v[10], v[11]), pack2(v[12], v[13]), pack2(v[14], v[15]));
      *(uint4*)(hrow + ((6 ^ s) << 3)) =
          make_uint4(pack2(v[16], v[17]), pack2(v[18], v[19]), pack2(v[20], v[21]), pack2(v[22], v[23]));
    } else {
      // dim z -> cols 56..67 (chunks 7,8) + zero pad 68..78 + selector col 79 (chunk 9)
      float v[12];
#pragma unroll
      for (int k = 0; k < 6; ++k) {
        float rev = nz * (0.5f * (float)(1 << k));
        float r = rev - rintf(rev);
        v[k] = __builtin_amdgcn_sinf(r);
        v[6 + k] = __builtin_amdgcn_cosf(r);
      }
      *(uint4*)(hrow + ((7 ^ s) << 3)) =
          make_uint4(pack2(v[0], v[1]), pack2(v[2], v[3]), pack2(v[4], v[5]), pack2(v[6], v[7]));
      *(uint4*)(hrow + ((8 ^ s) << 3)) =
          make_uint4(pack2(v[8], v[9]), pack2(v[10], v[11]), 0u, 0u);
      uint32 selw = sel ? 0x3F800000u : 0u;
      *(uint4*)(hrow + ((9 ^ s) << 3)) = make_uint4(0u, 0u, 0u, selw);
    }
  }
  __syncthreads();

  // ---- phase 2: MLP, wave = (mt-pair) x (jh-pair) ----
  const int w = t >> 6, L = t & 63;
  const int mt0 = (w & 1) * 2;   // mt pair {0,1} or {2,3}
  const int jq = w >> 1;         // point quadrant: rows jq*64 .. jq*64+63
  const int kh = L >> 5;
  const int prow0 = jq * 64 + (L & 31);
  const int prow1 = prow0 + 32;
  const int ps = prow0 & 15;     // == prow1 & 15
  const uint16_t* hrow0 = h_s + prow0 * 128;
  const uint16_t* hrow1 = h_s + prow1 * 128;
  uint16_t* arow0 = a_s + prow0 * 128;
  uint16_t* arow1 = a_s + prow1 * 128;

  mlp_layer<0, 5, 0,   true,  false>(hrow0, hrow1, arow0, arow1, wpack, bpack, mt0, kh, L, ps);
  mlp_layer<1, 8, 20,  false, false>(hrow0, hrow1, arow0, arow1, wpack, bpack, mt0, kh, L, ps);
  mlp_layer<2, 8, 52,  false, false>(hrow0, hrow1, arow0, arow1, wpack, bpack, mt0, kh, L, ps);
  mlp_layer<3, 5, 84,  true,  true >(hrow0, hrow1, arow0, arow1, wpack, bpack, mt0, kh, L, ps);
  mlp_layer<4, 8, 104, false, false>(hrow0, hrow1, arow0, arow1, wpack, bpack, mt0, kh, L, ps);
  mlp_layer<5, 8, 136, false, false>(hrow0, hrow1, arow0, arow1, wpack, bpack, mt0, kh, L, ps);

  // ---- output layer (w_out padded to 32x128): waves with mt0==0 handle their jq ----
  if (mt0 == 0) {
    short8 b0[8], b1[8];
#pragma unroll
    for (int k = 0; k < 8; ++k) {
      b0[k] = *(const short8*)(arow0 + (((2 * k + kh) ^ ps) << 3));
      b1[k] = *(const short8*)(arow1 + (((2 * k + kh) ^ ps) << 3));
    }
    floatx16 a0, a1;
    {
      const float4* bp = (const float4*)(bpack + 768 + kh * 16);
#pragma unroll
      for (int g = 0; g < 4; ++g) {
        float4 v = bp[g];
        a0[4 * g + 0] = v.x; a0[4 * g + 1] = v.y; a0[4 * g + 2] = v.z; a0[4 * g + 3] = v.w;
      }
      a1 = a0;
    }
    const uint16_t* wp = wpack + (size_t)168 * 512 + L * 8;
#pragma unroll
    for (int k = 0; k < 8; ++k) {
      short8 af = *(const short8*)(wp + k * 512);
      a0 = __builtin_amdgcn_mfma_f32_32x32x16_bf16(af, b0[k], a0, 0, 0, 0);
      a1 = __builtin_amdgcn_mfma_f32_32x32x16_bf16(af, b1[k], a1, 0, 0, 0);
    }
    if (kh == 0) {  // regs 0..3 = outputs 0..3
      const float l2e = 1.44269504f;
#pragma unroll
      for (int j = 0; j < 2; ++j) {
        const floatx16& ac = j ? a1 : a0;
        const int prow = j ? prow1 : prow0;
        const uint16_t* hrow = j ? hrow1 : hrow0;
        const int pg = blockIdx.x * 128 + prow;
        float r0 = 1.0f / (1.0f + exp2f(-l2e * ac[0]));
        float r1 = 1.0f / (1.0f + exp2f(-l2e * ac[1]));
        float r2 = 1.0f / (1.0f + exp2f(-l2e * ac[2]));
        uint16_t sv = hrow[((9 ^ ps) << 3) + 7];
        float dens = exp2f((ac[3] - 1.0f) * l2e) * (sv ? 1.0f : 0.0f);
        dout[pg * 3 + 0] = r0;
        dout[pg * 3 + 1] = r1;
        dout[pg * 3 + 2] = r2;
        dout[RGB_OFF + pg] = dens;
      }
    }
  }
}

extern "C" void kernel_launch(void* const* d_in, const int* in_sizes, int n_in,
                              void* d_out, int out_size, void* d_ws, size_t ws_size,
                              hipStream_t stream) {
  const float* tri = (const float*)d_in[0];
  const float* coords = (const float*)d_in[1];
  const float* w_in = (const float*)d_in[2];
  const float* b_in = (const float*)d_in[3];
  const float* w_skip = (const float*)d_in[4];
  const float* b_skip = (const float*)d_in[5];
  const float* w_bef = (const float*)d_in[6];
  const float* b_bef = (const float*)d_in[7];
  const float* w_aft = (const float*)d_in[8];
  const float* b_aft = (const float*)d_in[9];
  const float* w_out = (const float*)d_in[10];
  const float* b_out = (const float*)d_in[11];
  const size_t TRI_B = (size_t)12 * 256 * 256 * 32 * 2;  // 50,331,648
  const size_t WP_B = (size_t)176 * 1024;                // 180,224
  const size_t BP_B = 3200;
  char* ws = (char*)d_ws;
  const int fast = (ws_size >= TRI_B + WP_B + BP_B) ? 1 : 0;
  uint16_t* trit;
  uint16_t* wpk;
  float* bpk;
  if (fast) {
    trit = (uint16_t*)ws;
    wpk = (uint16_t*)(ws + TRI_B);
    bpk = (float*)(ws + TRI_B + WP_B);
  } else {
    trit = (uint16_t*)ws;  // unused
    wpk = (uint16_t*)ws;
    bpk = (float*)(ws + WP_B);
  }
  if (fast) k_tr<<<dim3(3072), dim3(256), 0, stream>>>(tri, trit);
  k_pack<<<dim3(45), dim3(256), 0, stream>>>(w_in, w_skip, w_bef, w_aft, w_out,
                                             b_in, b_skip, b_bef, b_aft, b_out,
                                             wpk, bpk);
  k_main<<<dim3(2048), dim3(256), 0, stream>>>(trit, tri, coords, wpk, bpk,
                                               (float*)d_out, fast);
}

// Round 4
// 272.246 us; speedup vs baseline: 27.3387x; 1.0224x over previous
//
#include <hip/hip_runtime.h>
#include <stdint.h>

typedef short short8 __attribute__((ext_vector_type(8)));
typedef float floatx16 __attribute__((ext_vector_type(16)));
typedef unsigned int uint32;

#define NPTS (4 * 65536)
#define RGB_OFF (NPTS * 3)

// ---------- helpers ----------
__device__ __forceinline__ uint16_t bf_rne(float f) {
  uint32 u = __float_as_uint(f);
  u += 0x7FFFu + ((u >> 16) & 1u);
  return (uint16_t)(u >> 16);
}
// pack two f32 -> two bf16 (round-half-up) via v_perm_b32
__device__ __forceinline__ uint32 pack2(float a, float b) {
  return __builtin_amdgcn_perm(__float_as_uint(b) + 0x8000u,
                               __float_as_uint(a) + 0x8000u, 0x07060302u);
}
__device__ __forceinline__ float bf_lo(uint32 u) { return __uint_as_float(u << 16); }
__device__ __forceinline__ float bf_hi(uint32 u) { return __uint_as_float(u & 0xFFFF0000u); }
// exchange: a's upper 32 lanes <-> b's lower 32 lanes
__device__ __forceinline__ void swap32(uint32& a, uint32& b) {
  asm("v_permlane32_swap_b32 %0, %1" : "+v"(a), "+v"(b));
}
__device__ __forceinline__ void gacc(const uint16_t* p, float w, float* acc) {
  uint4 q = *(const uint4*)p;
  acc[0] += w * bf_lo(q.x);
  acc[1] += w * bf_hi(q.x);
  acc[2] += w * bf_lo(q.y);
  acc[3] += w * bf_hi(q.y);
  acc[4] += w * bf_lo(q.z);
  acc[5] += w * bf_hi(q.z);
  acc[6] += w * bf_lo(q.w);
  acc[7] += w * bf_hi(q.w);
}

// ---------- kernel 1: triplane (12,32,256,256) f32 -> (12,256,256,32) bf16 ----------
__global__ __launch_bounds__(256) void k_tr(const float* __restrict__ tri,
                                            uint16_t* __restrict__ out) {
  __shared__ uint16_t tile[32 * 258];
  const int blk = blockIdx.x;  // 0..3071
  const int n = blk >> 8, y = blk & 255;
  const int t = threadIdx.x;
  for (int c = 0; c < 32; ++c) {
    float v = tri[((size_t)(n * 32 + c)) * 65536 + y * 256 + t];
    tile[c * 258 + t] = bf_rne(v);
  }
  __syncthreads();
  uint16_t* dst = out + ((size_t)(n * 256 + y)) * 256 * 32;
  const int c0 = (t & 7) * 4;
  for (int i = 0; i < 8; ++i) {
    int x = (t >> 3) + 32 * i;
    uint32 d0 = (uint32)tile[(c0 + 0) * 258 + x] | ((uint32)tile[(c0 + 1) * 258 + x] << 16);
    uint32 d1 = (uint32)tile[(c0 + 2) * 258 + x] | ((uint32)tile[(c0 + 3) * 258 + x] << 16);
    *(uint2*)(dst + x * 32 + c0) = make_uint2(d0, d1);
  }
}

// ---------- kernel 2: pack weights into MFMA A-frag layout + biases into C-layout ----------
// frag bases per layer: {0,20,52,84,104,136,168}, Ks={5,8,8,5,8,8,8}, 176 frags.
// frag(lay,mt,k): lane L holds W[mt*32+(L&31)][k*16+(L>>5)*8 + j], j=0..7 -> 16B
// packed-h column order: [feats 0..31 | freq 32..67 | pad 68..79].
__global__ __launch_bounds__(256) void k_pack(
    const float* __restrict__ w_in, const float* __restrict__ w_skip,
    const float* __restrict__ w_before, const float* __restrict__ w_after,
    const float* __restrict__ w_out, const float* __restrict__ b_in,
    const float* __restrict__ b_skip, const float* __restrict__ b_before,
    const float* __restrict__ b_after, const float* __restrict__ b_out,
    uint16_t* __restrict__ wpack, float* __restrict__ bpack) {
  const int blk = blockIdx.x;
  if (blk >= 44) {  // bias pack: bpack[l*128 + mt*32 + half*16 + reg]
    for (int t = threadIdx.x; t < 800; t += 256) {
      int l, idx;
      if (t < 768) { l = t >> 7; idx = t & 127; }
      else { l = 6; idx = t - 768; }
      int mt = idx >> 5, rem = idx & 31;
      int half = rem >> 4, r = rem & 15;
      int f = mt * 32 + (r & 3) + 8 * (r >> 2) + 4 * half;
      float v;
      switch (l) {
        case 0: v = b_in[f]; break;
        case 1: v = b_before[f]; break;
        case 2: v = b_before[128 + f]; break;
        case 3: v = b_skip[f]; break;
        case 4: v = b_after[f]; break;
        case 5: v = b_after[128 + f]; break;
        default: v = (f < 4) ? b_out[f] : 0.0f; break;
      }
      bpack[l * 128 + idx] = v;
    }
    return;
  }
  const int w = blk * 4 + (threadIdx.x >> 6);  // 0..175
  const int L = threadIdx.x & 63;
  int lay, mt, k;
  if (w < 20)      { lay = 0; mt = w / 5;        k = w - mt * 5; }
  else if (w < 52) { int u = w - 20;  lay = 1; mt = u >> 3; k = u & 7; }
  else if (w < 84) { int u = w - 52;  lay = 2; mt = u >> 3; k = u & 7; }
  else if (w < 104){ int u = w - 84;  lay = 3; mt = u / 5;  k = u - mt * 5; }
  else if (w < 136){ int u = w - 104; lay = 4; mt = u >> 3; k = u & 7; }
  else if (w < 168){ int u = w - 136; lay = 5; mt = u >> 3; k = u & 7; }
  else             { lay = 6; mt = 0; k = w - 168; }
  const float* W;
  int insk = 0;
  switch (lay) {
    case 0: W = w_in; insk = 1; break;
    case 1: W = w_before; break;
    case 2: W = w_before + 16384; break;
    case 3: W = w_skip; insk = 1; break;
    case 4: W = w_after; break;
    case 5: W = w_after + 16384; break;
    default: W = w_out; break;
  }
  const int frow = mt * 32 + (L & 31);
  const int kbase = k * 16 + (L >> 5) * 8;
  uint16_t h[8];
#pragma unroll
  for (int j = 0; j < 8; ++j) {
    int kl = kbase + j;
    float v;
    if (insk) {
      int col = (kl < 32) ? (36 + kl) : ((kl < 68) ? (kl - 32) : -1);
      v = (col < 0) ? 0.0f : W[frow * 68 + col];
    } else if (lay == 6) {
      v = (frow < 4) ? W[frow * 128 + kl] : 0.0f;
    } else {
      v = W[frow * 128 + kl];
    }
    h[j] = bf_rne(v);
  }
  uint4 q;
  q.x = (uint32)h[0] | ((uint32)h[1] << 16);
  q.y = (uint32)h[2] | ((uint32)h[3] << 16);
  q.z = (uint32)h[4] | ((uint32)h[5] << 16);
  q.w = (uint32)h[6] | ((uint32)h[7] << 16);
  *(uint4*)(wpack + (size_t)w * 512 + L * 8) = q;
}

// ---------- register-resident MLP machinery ----------
// C-layout (per 32-row tile): value(row r) at lane-half h=(r>>2)&1... specifically
// r = (reg&3) + 8*(reg>>2) + 4*(lane>>5). B-layout: lane-half t holds k = t*8+j.
// Frag f (global rows 16f..16f+15, s=f&1): B-frag regs = {q0a,q0b,q1a,q1b} after
// swap32(q0a,q1a), swap32(q0b,q1b), where qXa/qXb are packed quad (2s+X) pairs.

template <int LAY, int Ks, int FOFF>
__device__ __forceinline__ void mfma_block(floatx16* a, const short8* bin,
                                           const uint16_t* __restrict__ wpack,
                                           const float* __restrict__ bpack, int L,
                                           int kh) {
#pragma unroll
  for (int mt = 0; mt < 4; ++mt) {
    const float4* bp = (const float4*)(bpack + LAY * 128 + mt * 32 + kh * 16);
#pragma unroll
    for (int g = 0; g < 4; ++g) {
      float4 v = bp[g];
      a[mt][4 * g + 0] = v.x; a[mt][4 * g + 1] = v.y;
      a[mt][4 * g + 2] = v.z; a[mt][4 * g + 3] = v.w;
    }
  }
  const uint16_t* wp = wpack + (size_t)FOFF * 512 + L * 8;
#pragma unroll
  for (int k = 0; k < Ks; ++k) {
    short8 w0 = *(const short8*)(wp + (size_t)(0 * Ks + k) * 512);
    short8 w1 = *(const short8*)(wp + (size_t)(1 * Ks + k) * 512);
    short8 w2 = *(const short8*)(wp + (size_t)(2 * Ks + k) * 512);
    short8 w3 = *(const short8*)(wp + (size_t)(3 * Ks + k) * 512);
    a[0] = __builtin_amdgcn_mfma_f32_32x32x16_bf16(w0, bin[k], a[0], 0, 0, 0);
    a[1] = __builtin_amdgcn_mfma_f32_32x32x16_bf16(w1, bin[k], a[1], 0, 0, 0);
    a[2] = __builtin_amdgcn_mfma_f32_32x32x16_bf16(w2, bin[k], a[2], 0, 0, 0);
    a[3] = __builtin_amdgcn_mfma_f32_32x32x16_bf16(w3, bin[k], a[3], 0, 0, 0);
  }
}

template <int LAY, int Ks, int FOFF>
__device__ __forceinline__ void layer_dense(const short8* bin, short8* bout,
                                            const uint16_t* __restrict__ wpack,
                                            const float* __restrict__ bpack, int L,
                                            int kh) {
  floatx16 a[4];
  mfma_block<LAY, Ks, FOFF>(a, bin, wpack, bpack, L, kh);
#pragma unroll
  for (int f = 0; f < 8; ++f) {
    const int mt = f >> 1, s = f & 1;
    uint32 q0a = pack2(fmaxf(a[mt][8 * s + 0], 0.f), fmaxf(a[mt][8 * s + 1], 0.f));
    uint32 q0b = pack2(fmaxf(a[mt][8 * s + 2], 0.f), fmaxf(a[mt][8 * s + 3], 0.f));
    uint32 q1a = pack2(fmaxf(a[mt][8 * s + 4], 0.f), fmaxf(a[mt][8 * s + 5], 0.f));
    uint32 q1b = pack2(fmaxf(a[mt][8 * s + 6], 0.f), fmaxf(a[mt][8 * s + 7], 0.f));
    swap32(q0a, q1a);
    swap32(q0b, q1b);
    bout[f] = __builtin_bit_cast(short8, make_uint4(q0a, q0b, q1a, q1b));
  }
}

template <int LAY, int Ks, int FOFF>
__device__ __forceinline__ void layer_skip(const short8* hin, short8* bio,
                                           const uint16_t* __restrict__ wpack,
                                           const float* __restrict__ bpack, int L,
                                           int kh) {
  floatx16 a[4];
  mfma_block<LAY, Ks, FOFF>(a, hin, wpack, bpack, L, kh);
#pragma unroll
  for (int f = 0; f < 8; ++f) {
    const int mt = f >> 1, s = f & 1;
    uint4 old = __builtin_bit_cast(uint4, bio[f]);
    uint32 uA = old.x, uB = old.y, uC = old.z, uD = old.w;
    swap32(uA, uC);  // involution: back to C-layout packed x2
    swap32(uB, uD);
    float r0 = fmaxf(a[mt][8 * s + 0], 0.f) + bf_lo(uA);
    float r1 = fmaxf(a[mt][8 * s + 1], 0.f) + bf_hi(uA);
    float r2 = fmaxf(a[mt][8 * s + 2], 0.f) + bf_lo(uB);
    float r3 = fmaxf(a[mt][8 * s + 3], 0.f) + bf_hi(uB);
    float r4 = fmaxf(a[mt][8 * s + 4], 0.f) + bf_lo(uC);
    float r5 = fmaxf(a[mt][8 * s + 5], 0.f) + bf_hi(uC);
    float r6 = fmaxf(a[mt][8 * s + 6], 0.f) + bf_lo(uD);
    float r7 = fmaxf(a[mt][8 * s + 7], 0.f) + bf_hi(uD);
    uint32 q0a = pack2(r0, r1), q0b = pack2(r2, r3);
    uint32 q1a = pack2(r4, r5), q1b = pack2(r6, r7);
    swap32(q0a, q1a);
    swap32(q0b, q1b);
    bio[f] = __builtin_bit_cast(short8, make_uint4(q0a, q0b, q1a, q1b));
  }
}

// ---------- kernel 3: fused gather + encode + MLP, zero LDS / zero barriers ----------
// Wave owns 32 points. Lane L: point p = L&31, k-half kh = L>>5.
__global__ __launch_bounds__(256, 3) void k_main(
    const uint16_t* __restrict__ trit, const float* __restrict__ trif,
    const float* __restrict__ coords, const uint16_t* __restrict__ wpack,
    const float* __restrict__ bpack, float* __restrict__ dout, int fast) {
  const int t = threadIdx.x;
  const int L = t & 63;
  const int kh = L >> 5;
  const int p = (t >> 6) * 32 + (L & 31);
  const int pg = blockIdx.x * 128 + p;

  // ---- phase 1: gather + freq encode, directly into B-frag registers ----
  float cx = coords[pg * 3 + 0], cy = coords[pg * 3 + 1], cz = coords[pg * 3 + 2];
  float f1x = cx + 1.0f, f1y = cy + 1.0f, f1z = cz + 1.0f;
  float nx = f1x * 0.5f, ny = f1y * 0.5f, nz = f1z * 0.5f;
  float sx = f1x - 1.0f, sy = f1y - 1.0f, sz = f1z - 1.0f;
  bool sel = (nx > 0.f) & (nx < 1.f) & (ny > 0.f) & (ny < 1.f) & (nz > 0.f) & (nz < 1.f);
  const int b = pg >> 16;
  float acc[16];
#pragma unroll
  for (int j = 0; j < 16; ++j) acc[j] = 0.f;
#pragma unroll
  for (int pl = 0; pl < 3; ++pl) {
    float gx = (pl == 2) ? sy : sx;
    float gy = (pl == 0) ? sy : sz;
    float ix = ((gx + 1.0f) * 0.5f) * 255.0f;
    float iy = ((gy + 1.0f) * 0.5f) * 255.0f;
    float x0f = floorf(ix), y0f = floorf(iy);
    float wx = ix - x0f, wy = iy - y0f;
    float vx0 = (x0f >= 0.0f && x0f < 256.0f) ? 1.f : 0.f;
    float vx1 = (x0f >= -1.0f && x0f < 255.0f) ? 1.f : 0.f;
    float vy0 = (y0f >= 0.0f && y0f < 256.0f) ? 1.f : 0.f;
    float vy1 = (y0f >= -1.0f && y0f < 255.0f) ? 1.f : 0.f;
    int x0 = min(max((int)x0f, 0), 255), x1 = min(max((int)x0f + 1, 0), 255);
    int y0 = min(max((int)y0f, 0), 255), y1 = min(max((int)y0f + 1, 0), 255);
    float w00 = (1.f - wx) * (1.f - wy) * vx0 * vy0;
    float w10 = wx * (1.f - wy) * vx1 * vy0;
    float w01 = (1.f - wx) * wy * vx0 * vy1;
    float w11 = wx * wy * vx1 * vy1;
    const int n = 3 * b + pl;
    if (fast) {
      // lane's channel chunks: [kh*8, kh*8+8) and [16+kh*8, ...)
      const uint16_t* cb = trit + ((size_t)n << 21) + kh * 8;
      size_t o00 = (size_t)(y0 * 256 + x0) << 5, o10 = (size_t)(y0 * 256 + x1) << 5;
      size_t o01 = (size_t)(y1 * 256 + x0) << 5, o11 = (size_t)(y1 * 256 + x1) << 5;
      gacc(cb + o00, w00, acc); gacc(cb + 16 + o00, w00, acc + 8);
      gacc(cb + o10, w10, acc); gacc(cb + 16 + o10, w10, acc + 8);
      gacc(cb + o01, w01, acc); gacc(cb + 16 + o01, w01, acc + 8);
      gacc(cb + o11, w11, acc); gacc(cb + 16 + o11, w11, acc + 8);
    } else {
      const float* basef = trif + (((size_t)n * 32) << 16);
#pragma unroll
      for (int j = 0; j < 8; ++j) {
        const float* c0p = basef + (((size_t)(kh * 8 + j)) << 16);
        const float* c1p = basef + (((size_t)(16 + kh * 8 + j)) << 16);
        acc[j] += w00 * c0p[y0 * 256 + x0] + w10 * c0p[y0 * 256 + x1] +
                  w01 * c0p[y1 * 256 + x0] + w11 * c0p[y1 * 256 + x1];
        acc[8 + j] += w00 * c1p[y0 * 256 + x0] + w10 * c1p[y0 * 256 + x1] +
                      w01 * c1p[y1 * 256 + x0] + w11 * c1p[y1 * 256 + x1];
      }
    }
  }
  short8 hf[5];
  hf[0] = __builtin_bit_cast(
      short8, make_uint4(pack2(acc[0], acc[1]), pack2(acc[2], acc[3]),
                         pack2(acc[4], acc[5]), pack2(acc[6], acc[7])));
  hf[1] = __builtin_bit_cast(
      short8, make_uint4(pack2(acc[8], acc[9]), pack2(acc[10], acc[11]),
                         pack2(acc[12], acc[13]), pack2(acc[14], acc[15])));
  {
    // freq cols 32+e, e = d*12 + (sin: k | cos: 6+k)
    float sv[3][6], cv[3][6];
#pragma unroll
    for (int d = 0; d < 3; ++d) {
      float nd = (d == 0) ? nx : (d == 1) ? ny : nz;
#pragma unroll
      for (int k = 0; k < 6; ++k) {
        float rev = nd * (0.5f * (float)(1 << k));
        float r = rev - rintf(rev);
        sv[d][k] = __builtin_amdgcn_sinf(r);
        cv[d][k] = __builtin_amdgcn_cosf(r);
      }
    }
    if (kh == 0) {
      hf[2] = __builtin_bit_cast(  // e 0..7: d0 s0-5, d0 c0-1
          short8, make_uint4(pack2(sv[0][0], sv[0][1]), pack2(sv[0][2], sv[0][3]),
                             pack2(sv[0][4], sv[0][5]), pack2(cv[0][0], cv[0][1])));
      hf[3] = __builtin_bit_cast(  // e 16..23: d1 s4-5, d1 c0-5
          short8, make_uint4(pack2(sv[1][4], sv[1][5]), pack2(cv[1][0], cv[1][1]),
                             pack2(cv[1][2], cv[1][3]), pack2(cv[1][4], cv[1][5])));
      hf[4] = __builtin_bit_cast(  // e 32..35: d2 c2-5, then pad
          short8, make_uint4(pack2(cv[2][2], cv[2][3]), pack2(cv[2][4], cv[2][5]), 0u, 0u));
    } else {
      hf[2] = __builtin_bit_cast(  // e 8..15: d0 c2-5, d1 s0-3
          short8, make_uint4(pack2(cv[0][2], cv[0][3]), pack2(cv[0][4], cv[0][5]),
                             pack2(sv[1][0], sv[1][1]), pack2(sv[1][2], sv[1][3])));
      hf[3] = __builtin_bit_cast(  // e 24..31: d2 s0-5, d2 c0-1
          short8, make_uint4(pack2(sv[2][0], sv[2][1]), pack2(sv[2][2], sv[2][3]),
                             pack2(sv[2][4], sv[2][5]), pack2(cv[2][0], cv[2][1])));
      hf[4] = __builtin_bit_cast(short8, make_uint4(0u, 0u, 0u, 0u));
    }
  }

  // ---- phase 2: MLP, activations register-resident ----
  short8 bf[8];
  layer_dense<0, 5, 0>(hf, bf, wpack, bpack, L, kh);
  layer_dense<1, 8, 20>(bf, bf, wpack, bpack, L, kh);
  layer_dense<2, 8, 52>(bf, bf, wpack, bpack, L, kh);
  layer_skip<3, 5, 84>(hf, bf, wpack, bpack, L, kh);
  layer_dense<4, 8, 104>(bf, bf, wpack, bpack, L, kh);
  layer_dense<5, 8, 136>(bf, bf, wpack, bpack, L, kh);

  // ---- output layer: w_out padded to 32x128, only rows 0..3 real ----
  {
    floatx16 a;
    const float4* bp = (const float4*)(bpack + 768 + kh * 16);
#pragma unroll
    for (int g = 0; g < 4; ++g) {
      float4 v = bp[g];
      a[4 * g + 0] = v.x; a[4 * g + 1] = v.y; a[4 * g + 2] = v.z; a[4 * g + 3] = v.w;
    }
    const uint16_t* wp = wpack + (size_t)168 * 512 + L * 8;
#pragma unroll
    for (int k = 0; k < 8; ++k) {
      short8 af = *(const short8*)(wp + (size_t)k * 512);
      a = __builtin_amdgcn_mfma_f32_32x32x16_bf16(af, bf[k], a, 0, 0, 0);
    }
    if (kh == 0) {  // regs 0..3 = out features 0..3 for point pg
      const float l2e = 1.44269504f;
      float r0 = 1.0f / (1.0f + exp2f(-l2e * a[0]));
      float r1 = 1.0f / (1.0f + exp2f(-l2e * a[1]));
      float r2 = 1.0f / (1.0f + exp2f(-l2e * a[2]));
      float dens = exp2f((a[3] - 1.0f) * l2e) * (sel ? 1.0f : 0.0f);
      dout[pg * 3 + 0] = r0;
      dout[pg * 3 + 1] = r1;
      dout[pg * 3 + 2] = r2;
      dout[RGB_OFF + pg] = dens;
    }
  }
}

extern "C" void kernel_launch(void* const* d_in, const int* in_sizes, int n_in,
                              void* d_out, int out_size, void* d_ws, size_t ws_size,
                              hipStream_t stream) {
  const float* tri = (const float*)d_in[0];
  const float* coords = (const float*)d_in[1];
  const float* w_in = (const float*)d_in[2];
  const float* b_in = (const float*)d_in[3];
  const float* w_skip = (const float*)d_in[4];
  const float* b_skip = (const float*)d_in[5];
  const float* w_bef = (const float*)d_in[6];
  const float* b_bef = (const float*)d_in[7];
  const float* w_aft = (const float*)d_in[8];
  const float* b_aft = (const float*)d_in[9];
  const float* w_out = (const float*)d_in[10];
  const float* b_out = (const float*)d_in[11];
  const size_t TRI_B = (size_t)12 * 256 * 256 * 32 * 2;  // 50,331,648
  const size_t WP_B = (size_t)176 * 1024;                // 180,224
  const size_t BP_B = 3200;
  char* ws = (char*)d_ws;
  const int fast = (ws_size >= TRI_B + WP_B + BP_B) ? 1 : 0;
  uint16_t* trit;
  uint16_t* wpk;
  float* bpk;
  if (fast) {
    trit = (uint16_t*)ws;
    wpk = (uint16_t*)(ws + TRI_B);
    bpk = (float*)(ws + TRI_B + WP_B);
  } else {
    trit = (uint16_t*)ws;  // unused
    wpk = (uint16_t*)ws;
    bpk = (float*)(ws + WP_B);
  }
  if (fast) k_tr<<<dim3(3072), dim3(256), 0, stream>>>(tri, trit);
  k_pack<<<dim3(45), dim3(256), 0, stream>>>(w_in, w_skip, w_bef, w_aft, w_out,
                                             b_in, b_skip, b_bef, b_aft, b_out,
                                             wpk, bpk);
  k_main<<<dim3(2048), dim3(256), 0, stream>>>(trit, tri, coords, wpk, bpk,
                                               (float*)d_out, fast);
}

// Round 5
// 267.381 us; speedup vs baseline: 27.8361x; 1.0182x over previous
//
#include <hip/hip_runtime.h>
#include <stdint.h>

typedef short short8 __attribute__((ext_vector_type(8)));
typedef float floatx16 __attribute__((ext_vector_type(16)));
typedef unsigned int uint32;

#define NPTS (4 * 65536)
#define RGB_OFF (NPTS * 3)

// ---------- helpers ----------
__device__ __forceinline__ uint16_t bf_rne(float f) {
  uint32 u = __float_as_uint(f);
  u += 0x7FFFu + ((u >> 16) & 1u);
  return (uint16_t)(u >> 16);
}
// pack two f32 -> two bf16 (round-half-up) via v_perm_b32
__device__ __forceinline__ uint32 pack2(float a, float b) {
  return __builtin_amdgcn_perm(__float_as_uint(b) + 0x8000u,
                               __float_as_uint(a) + 0x8000u, 0x07060302u);
}
__device__ __forceinline__ float bf_lo(uint32 u) { return __uint_as_float(u << 16); }
__device__ __forceinline__ float bf_hi(uint32 u) { return __uint_as_float(u & 0xFFFF0000u); }
// exchange: a's upper 32 lanes <-> b's lower 32 lanes
__device__ __forceinline__ void swap32(uint32& a, uint32& b) {
  asm("v_permlane32_swap_b32 %0, %1" : "+v"(a), "+v"(b));
}
__device__ __forceinline__ void gacc(const uint16_t* p, float w, float* acc) {
  uint4 q = *(const uint4*)p;
  acc[0] += w * bf_lo(q.x);
  acc[1] += w * bf_hi(q.x);
  acc[2] += w * bf_lo(q.y);
  acc[3] += w * bf_hi(q.y);
  acc[4] += w * bf_lo(q.z);
  acc[5] += w * bf_hi(q.z);
  acc[6] += w * bf_lo(q.w);
  acc[7] += w * bf_hi(q.w);
}

// ---------- kernel 1: triplane (12,32,256,256) f32 -> (12,256,256,32) bf16 ----------
// Streaming, LDS-free: thread = output pixel, 32 coalesced channel reads,
// one contiguous 64B store.
__global__ __launch_bounds__(256) void k_tr(const float* __restrict__ tri,
                                            uint16_t* __restrict__ out) {
  const size_t P = (size_t)blockIdx.x * 256 + threadIdx.x;  // pixel 0..786431
  const int n = (int)(P >> 16);
  const int rem = (int)(P & 65535);
  const float* src = tri + ((size_t)n << 21) + rem;
  uint32 q[16];
#pragma unroll
  for (int c = 0; c < 16; ++c) {
    float a = src[(size_t)(2 * c) << 16];
    float b = src[(size_t)(2 * c + 1) << 16];
    q[c] = pack2(a, b);
  }
  uint4* dst = (uint4*)(out + P * 32);
  dst[0] = make_uint4(q[0], q[1], q[2], q[3]);
  dst[1] = make_uint4(q[4], q[5], q[6], q[7]);
  dst[2] = make_uint4(q[8], q[9], q[10], q[11]);
  dst[3] = make_uint4(q[12], q[13], q[14], q[15]);
}

// ---------- kernel 2: pack weights into MFMA A-frag layout + biases into C-layout ----------
// frag bases per layer: {0,20,52,84,104,136,168}, Ks={5,8,8,5,8,8,8}, 176 frags.
// frag(lay,mt,k): lane L holds W[mt*32+(L&31)][k*16+(L>>5)*8 + j], j=0..7 -> 16B
// packed-h column order: [feats 0..31 | freq 32..67 | pad 68..79].
__global__ __launch_bounds__(256) void k_pack(
    const float* __restrict__ w_in, const float* __restrict__ w_skip,
    const float* __restrict__ w_before, const float* __restrict__ w_after,
    const float* __restrict__ w_out, const float* __restrict__ b_in,
    const float* __restrict__ b_skip, const float* __restrict__ b_before,
    const float* __restrict__ b_after, const float* __restrict__ b_out,
    uint16_t* __restrict__ wpack, float* __restrict__ bpack) {
  const int blk = blockIdx.x;
  if (blk >= 44) {  // bias pack: bpack[l*128 + mt*32 + half*16 + reg]
    for (int t = threadIdx.x; t < 800; t += 256) {
      int l, idx;
      if (t < 768) { l = t >> 7; idx = t & 127; }
      else { l = 6; idx = t - 768; }
      int mt = idx >> 5, rem = idx & 31;
      int half = rem >> 4, r = rem & 15;
      int f = mt * 32 + (r & 3) + 8 * (r >> 2) + 4 * half;
      float v;
      switch (l) {
        case 0: v = b_in[f]; break;
        case 1: v = b_before[f]; break;
        case 2: v = b_before[128 + f]; break;
        case 3: v = b_skip[f]; break;
        case 4: v = b_after[f]; break;
        case 5: v = b_after[128 + f]; break;
        default: v = (f < 4) ? b_out[f] : 0.0f; break;
      }
      bpack[l * 128 + idx] = v;
    }
    return;
  }
  const int w = blk * 4 + (threadIdx.x >> 6);  // 0..175
  const int L = threadIdx.x & 63;
  int lay, mt, k;
  if (w < 20)      { lay = 0; mt = w / 5;        k = w - mt * 5; }
  else if (w < 52) { int u = w - 20;  lay = 1; mt = u >> 3; k = u & 7; }
  else if (w < 84) { int u = w - 52;  lay = 2; mt = u >> 3; k = u & 7; }
  else if (w < 104){ int u = w - 84;  lay = 3; mt = u / 5;  k = u - mt * 5; }
  else if (w < 136){ int u = w - 104; lay = 4; mt = u >> 3; k = u & 7; }
  else if (w < 168){ int u = w - 136; lay = 5; mt = u >> 3; k = u & 7; }
  else             { lay = 6; mt = 0; k = w - 168; }
  const float* W;
  int insk = 0;
  switch (lay) {
    case 0: W = w_in; insk = 1; break;
    case 1: W = w_before; break;
    case 2: W = w_before + 16384; break;
    case 3: W = w_skip; insk = 1; break;
    case 4: W = w_after; break;
    case 5: W = w_after + 16384; break;
    default: W = w_out; break;
  }
  const int frow = mt * 32 + (L & 31);
  const int kbase = k * 16 + (L >> 5) * 8;
  uint16_t h[8];
#pragma unroll
  for (int j = 0; j < 8; ++j) {
    int kl = kbase + j;
    float v;
    if (insk) {
      int col = (kl < 32) ? (36 + kl) : ((kl < 68) ? (kl - 32) : -1);
      v = (col < 0) ? 0.0f : W[frow * 68 + col];
    } else if (lay == 6) {
      v = (frow < 4) ? W[frow * 128 + kl] : 0.0f;
    } else {
      v = W[frow * 128 + kl];
    }
    h[j] = bf_rne(v);
  }
  uint4 q;
  q.x = (uint32)h[0] | ((uint32)h[1] << 16);
  q.y = (uint32)h[2] | ((uint32)h[3] << 16);
  q.z = (uint32)h[4] | ((uint32)h[5] << 16);
  q.w = (uint32)h[6] | ((uint32)h[7] << 16);
  *(uint4*)(wpack + (size_t)w * 512 + L * 8) = q;
}

// ---------- weight staging: global -> LDS, cooperative over 256 threads ----------
// NFRAG KB copied; chunk counts are multiples of 256 for all layers (no bounds).
template <int NFRAG>
__device__ __forceinline__ void stage(const uint16_t* __restrict__ wp_base,
                                      uint16_t* __restrict__ wbuf, int t) {
#pragma unroll
  for (int i = 0; i < NFRAG * 64 / 256; ++i) {
    const int g = t + i * 256;  // 16B chunk index
    uint4 v = *(const uint4*)(wp_base + g * 8);
    *(uint4*)(wbuf + g * 8) = v;
  }
}

// ---------- register-resident MLP machinery (weights from LDS) ----------
template <int LAY, int Ks>
__device__ __forceinline__ void mfma_block(floatx16* a, const short8* bin,
                                           const uint16_t* __restrict__ wbuf,
                                           const float* __restrict__ bpack, int L,
                                           int kh) {
#pragma unroll
  for (int mt = 0; mt < 4; ++mt) {
    const float4* bp = (const float4*)(bpack + LAY * 128 + mt * 32 + kh * 16);
#pragma unroll
    for (int g = 0; g < 4; ++g) {
      float4 v = bp[g];
      a[mt][4 * g + 0] = v.x; a[mt][4 * g + 1] = v.y;
      a[mt][4 * g + 2] = v.z; a[mt][4 * g + 3] = v.w;
    }
  }
  const uint16_t* wp = wbuf + L * 8;
#pragma unroll
  for (int k = 0; k < Ks; ++k) {
    short8 w0 = *(const short8*)(wp + (size_t)(0 * Ks + k) * 512);
    short8 w1 = *(const short8*)(wp + (size_t)(1 * Ks + k) * 512);
    short8 w2 = *(const short8*)(wp + (size_t)(2 * Ks + k) * 512);
    short8 w3 = *(const short8*)(wp + (size_t)(3 * Ks + k) * 512);
    a[0] = __builtin_amdgcn_mfma_f32_32x32x16_bf16(w0, bin[k], a[0], 0, 0, 0);
    a[1] = __builtin_amdgcn_mfma_f32_32x32x16_bf16(w1, bin[k], a[1], 0, 0, 0);
    a[2] = __builtin_amdgcn_mfma_f32_32x32x16_bf16(w2, bin[k], a[2], 0, 0, 0);
    a[3] = __builtin_amdgcn_mfma_f32_32x32x16_bf16(w3, bin[k], a[3], 0, 0, 0);
  }
}

template <int LAY, int Ks>
__device__ __forceinline__ void layer_dense(const short8* bin, short8* bout,
                                            const uint16_t* __restrict__ wbuf,
                                            const float* __restrict__ bpack, int L,
                                            int kh) {
  floatx16 a[4];
  mfma_block<LAY, Ks>(a, bin, wbuf, bpack, L, kh);
#pragma unroll
  for (int f = 0; f < 8; ++f) {
    const int mt = f >> 1, s = f & 1;
    uint32 q0a = pack2(fmaxf(a[mt][8 * s + 0], 0.f), fmaxf(a[mt][8 * s + 1], 0.f));
    uint32 q0b = pack2(fmaxf(a[mt][8 * s + 2], 0.f), fmaxf(a[mt][8 * s + 3], 0.f));
    uint32 q1a = pack2(fmaxf(a[mt][8 * s + 4], 0.f), fmaxf(a[mt][8 * s + 5], 0.f));
    uint32 q1b = pack2(fmaxf(a[mt][8 * s + 6], 0.f), fmaxf(a[mt][8 * s + 7], 0.f));
    swap32(q0a, q1a);
    swap32(q0b, q1b);
    bout[f] = __builtin_bit_cast(short8, make_uint4(q0a, q0b, q1a, q1b));
  }
}

template <int LAY, int Ks>
__device__ __forceinline__ void layer_skip(const short8* hin, short8* bio,
                                           const uint16_t* __restrict__ wbuf,
                                           const float* __restrict__ bpack, int L,
                                           int kh) {
  floatx16 a[4];
  mfma_block<LAY, Ks>(a, hin, wbuf, bpack, L, kh);
#pragma unroll
  for (int f = 0; f < 8; ++f) {
    const int mt = f >> 1, s = f & 1;
    uint4 old = __builtin_bit_cast(uint4, bio[f]);
    uint32 uA = old.x, uB = old.y, uC = old.z, uD = old.w;
    swap32(uA, uC);  // involution: back to C-layout packed x2
    swap32(uB, uD);
    float r0 = fmaxf(a[mt][8 * s + 0], 0.f) + bf_lo(uA);
    float r1 = fmaxf(a[mt][8 * s + 1], 0.f) + bf_hi(uA);
    float r2 = fmaxf(a[mt][8 * s + 2], 0.f) + bf_lo(uB);
    float r3 = fmaxf(a[mt][8 * s + 3], 0.f) + bf_hi(uB);
    float r4 = fmaxf(a[mt][8 * s + 4], 0.f) + bf_lo(uC);
    float r5 = fmaxf(a[mt][8 * s + 5], 0.f) + bf_hi(uC);
    float r6 = fmaxf(a[mt][8 * s + 6], 0.f) + bf_lo(uD);
    float r7 = fmaxf(a[mt][8 * s + 7], 0.f) + bf_hi(uD);
    uint32 q0a = pack2(r0, r1), q0b = pack2(r2, r3);
    uint32 q1a = pack2(r4, r5), q1b = pack2(r6, r7);
    swap32(q0a, q1a);
    swap32(q0b, q1b);
    bio[f] = __builtin_bit_cast(short8, make_uint4(q0a, q0b, q1a, q1b));
  }
}

// ---------- kernel 3: fused gather + encode + MLP ----------
// Wave owns 32 points; activations register-resident; weights staged layer-by-layer
// into a single 32KB LDS buffer shared by the block's 4 waves.
__global__ __launch_bounds__(256, 3) void k_main(
    const uint16_t* __restrict__ trit, const float* __restrict__ trif,
    const float* __restrict__ coords, const uint16_t* __restrict__ wpack,
    const float* __restrict__ bpack, float* __restrict__ dout, int fast) {
  __shared__ __align__(16) uint16_t wbuf[16384];  // 32KB: one layer's frags
  const int t = threadIdx.x;
  const int L = t & 63;
  const int kh = L >> 5;
  const int p = (t >> 6) * 32 + (L & 31);
  const int pg = blockIdx.x * 128 + p;

  // stage layer-0 weights early; copy overlaps the gather loads below
  stage<20>(wpack, wbuf, t);

  // ---- phase 1: gather + freq encode, directly into B-frag registers ----
  float cx = coords[pg * 3 + 0], cy = coords[pg * 3 + 1], cz = coords[pg * 3 + 2];
  float f1x = cx + 1.0f, f1y = cy + 1.0f, f1z = cz + 1.0f;
  float nx = f1x * 0.5f, ny = f1y * 0.5f, nz = f1z * 0.5f;
  float sx = f1x - 1.0f, sy = f1y - 1.0f, sz = f1z - 1.0f;
  bool sel = (nx > 0.f) & (nx < 1.f) & (ny > 0.f) & (ny < 1.f) & (nz > 0.f) & (nz < 1.f);
  const int b = pg >> 16;
  float acc[16];
#pragma unroll
  for (int j = 0; j < 16; ++j) acc[j] = 0.f;
#pragma unroll
  for (int pl = 0; pl < 3; ++pl) {
    float gx = (pl == 2) ? sy : sx;
    float gy = (pl == 0) ? sy : sz;
    float ix = ((gx + 1.0f) * 0.5f) * 255.0f;
    float iy = ((gy + 1.0f) * 0.5f) * 255.0f;
    float x0f = floorf(ix), y0f = floorf(iy);
    float wx = ix - x0f, wy = iy - y0f;
    float vx0 = (x0f >= 0.0f && x0f < 256.0f) ? 1.f : 0.f;
    float vx1 = (x0f >= -1.0f && x0f < 255.0f) ? 1.f : 0.f;
    float vy0 = (y0f >= 0.0f && y0f < 256.0f) ? 1.f : 0.f;
    float vy1 = (y0f >= -1.0f && y0f < 255.0f) ? 1.f : 0.f;
    int x0 = min(max((int)x0f, 0), 255), x1 = min(max((int)x0f + 1, 0), 255);
    int y0 = min(max((int)y0f, 0), 255), y1 = min(max((int)y0f + 1, 0), 255);
    float w00 = (1.f - wx) * (1.f - wy) * vx0 * vy0;
    float w10 = wx * (1.f - wy) * vx1 * vy0;
    float w01 = (1.f - wx) * wy * vx0 * vy1;
    float w11 = wx * wy * vx1 * vy1;
    const int n = 3 * b + pl;
    if (fast) {
      // lane's channel chunks: [kh*8, kh*8+8) and [16+kh*8, ...)
      const uint16_t* cb = trit + ((size_t)n << 21) + kh * 8;
      size_t o00 = (size_t)(y0 * 256 + x0) << 5, o10 = (size_t)(y0 * 256 + x1) << 5;
      size_t o01 = (size_t)(y1 * 256 + x0) << 5, o11 = (size_t)(y1 * 256 + x1) << 5;
      gacc(cb + o00, w00, acc); gacc(cb + 16 + o00, w00, acc + 8);
      gacc(cb + o10, w10, acc); gacc(cb + 16 + o10, w10, acc + 8);
      gacc(cb + o01, w01, acc); gacc(cb + 16 + o01, w01, acc + 8);
      gacc(cb + o11, w11, acc); gacc(cb + 16 + o11, w11, acc + 8);
    } else {
      const float* basef = trif + (((size_t)n * 32) << 16);
#pragma unroll
      for (int j = 0; j < 8; ++j) {
        const float* c0p = basef + (((size_t)(kh * 8 + j)) << 16);
        const float* c1p = basef + (((size_t)(16 + kh * 8 + j)) << 16);
        acc[j] += w00 * c0p[y0 * 256 + x0] + w10 * c0p[y0 * 256 + x1] +
                  w01 * c0p[y1 * 256 + x0] + w11 * c0p[y1 * 256 + x1];
        acc[8 + j] += w00 * c1p[y0 * 256 + x0] + w10 * c1p[y0 * 256 + x1] +
                      w01 * c1p[y1 * 256 + x0] + w11 * c1p[y1 * 256 + x1];
      }
    }
  }
  short8 hf[5];
  hf[0] = __builtin_bit_cast(
      short8, make_uint4(pack2(acc[0], acc[1]), pack2(acc[2], acc[3]),
                         pack2(acc[4], acc[5]), pack2(acc[6], acc[7])));
  hf[1] = __builtin_bit_cast(
      short8, make_uint4(pack2(acc[8], acc[9]), pack2(acc[10], acc[11]),
                         pack2(acc[12], acc[13]), pack2(acc[14], acc[15])));
  {
    // freq cols 32+e, e = d*12 + (sin: k | cos: 6+k)
    float sv[3][6], cv[3][6];
#pragma unroll
    for (int d = 0; d < 3; ++d) {
      float nd = (d == 0) ? nx : (d == 1) ? ny : nz;
#pragma unroll
      for (int k = 0; k < 6; ++k) {
        float rev = nd * (0.5f * (float)(1 << k));
        float r = rev - rintf(rev);
        sv[d][k] = __builtin_amdgcn_sinf(r);
        cv[d][k] = __builtin_amdgcn_cosf(r);
      }
    }
    if (kh == 0) {
      hf[2] = __builtin_bit_cast(  // e 0..7: d0 s0-5, d0 c0-1
          short8, make_uint4(pack2(sv[0][0], sv[0][1]), pack2(sv[0][2], sv[0][3]),
                             pack2(sv[0][4], sv[0][5]), pack2(cv[0][0], cv[0][1])));
      hf[3] = __builtin_bit_cast(  // e 16..23: d1 s4-5, d1 c0-5
          short8, make_uint4(pack2(sv[1][4], sv[1][5]), pack2(cv[1][0], cv[1][1]),
                             pack2(cv[1][2], cv[1][3]), pack2(cv[1][4], cv[1][5])));
      hf[4] = __builtin_bit_cast(  // e 32..35: d2 c2-5, then pad
          short8, make_uint4(pack2(cv[2][2], cv[2][3]), pack2(cv[2][4], cv[2][5]), 0u, 0u));
    } else {
      hf[2] = __builtin_bit_cast(  // e 8..15: d0 c2-5, d1 s0-3
          short8, make_uint4(pack2(cv[0][2], cv[0][3]), pack2(cv[0][4], cv[0][5]),
                             pack2(sv[1][0], sv[1][1]), pack2(sv[1][2], sv[1][3])));
      hf[3] = __builtin_bit_cast(  // e 24..31: d2 s0-5, d2 c0-1
          short8, make_uint4(pack2(sv[2][0], sv[2][1]), pack2(sv[2][2], sv[2][3]),
                             pack2(sv[2][4], sv[2][5]), pack2(cv[2][0], cv[2][1])));
      hf[4] = __builtin_bit_cast(short8, make_uint4(0u, 0u, 0u, 0u));
    }
  }

  // ---- phase 2: MLP; weights staged per layer into shared wbuf ----
  short8 bf[8];
  __syncthreads();  // wbuf(layer0) ready
  layer_dense<0, 5>(hf, bf, wbuf, bpack, L, kh);
  __syncthreads(); stage<32>(wpack + (size_t)20 * 512, wbuf, t); __syncthreads();
  layer_dense<1, 8>(bf, bf, wbuf, bpack, L, kh);
  __syncthreads(); stage<32>(wpack + (size_t)52 * 512, wbuf, t); __syncthreads();
  layer_dense<2, 8>(bf, bf, wbuf, bpack, L, kh);
  __syncthreads(); stage<20>(wpack + (size_t)84 * 512, wbuf, t); __syncthreads();
  layer_skip<3, 5>(hf, bf, wbuf, bpack, L, kh);
  __syncthreads(); stage<32>(wpack + (size_t)104 * 512, wbuf, t); __syncthreads();
  layer_dense<4, 8>(bf, bf, wbuf, bpack, L, kh);
  __syncthreads(); stage<32>(wpack + (size_t)136 * 512, wbuf, t); __syncthreads();
  layer_dense<5, 8>(bf, bf, wbuf, bpack, L, kh);
  __syncthreads(); stage<8>(wpack + (size_t)168 * 512, wbuf, t); __syncthreads();

  // ---- output layer: w_out padded to 32x128, only rows 0..3 real ----
  {
    floatx16 a;
    const float4* bp = (const float4*)(bpack + 768 + kh * 16);
#pragma unroll
    for (int g = 0; g < 4; ++g) {
      float4 v = bp[g];
      a[4 * g + 0] = v.x; a[4 * g + 1] = v.y; a[4 * g + 2] = v.z; a[4 * g + 3] = v.w;
    }
    const uint16_t* wp = wbuf + L * 8;
#pragma unroll
    for (int k = 0; k < 8; ++k) {
      short8 af = *(const short8*)(wp + (size_t)k * 512);
      a = __builtin_amdgcn_mfma_f32_32x32x16_bf16(af, bf[k], a, 0, 0, 0);
    }
    if (kh == 0) {  // regs 0..3 = out features 0..3 for point pg
      const float l2e = 1.44269504f;
      float r0 = 1.0f / (1.0f + exp2f(-l2e * a[0]));
      float r1 = 1.0f / (1.0f + exp2f(-l2e * a[1]));
      float r2 = 1.0f / (1.0f + exp2f(-l2e * a[2]));
      float dens = exp2f((a[3] - 1.0f) * l2e) * (sel ? 1.0f : 0.0f);
      dout[pg * 3 + 0] = r0;
      dout[pg * 3 + 1] = r1;
      dout[pg * 3 + 2] = r2;
      dout[RGB_OFF + pg] = dens;
    }
  }
}

extern "C" void kernel_launch(void* const* d_in, const int* in_sizes, int n_in,
                              void* d_out, int out_size, void* d_ws, size_t ws_size,
                              hipStream_t stream) {
  const float* tri = (const float*)d_in[0];
  const float* coords = (const float*)d_in[1];
  const float* w_in = (const float*)d_in[2];
  const float* b_in = (const float*)d_in[3];
  const float* w_skip = (const float*)d_in[4];
  const float* b_skip = (const float*)d_in[5];
  const float* w_bef = (const float*)d_in[6];
  const float* b_bef = (const float*)d_in[7];
  const float* w_aft = (const float*)d_in[8];
  const float* b_aft = (const float*)d_in[9];
  const float* w_out = (const float*)d_in[10];
  const float* b_out = (const float*)d_in[11];
  const size_t TRI_B = (size_t)12 * 256 * 256 * 32 * 2;  // 50,331,648
  const size_t WP_B = (size_t)176 * 1024;                // 180,224
  const size_t BP_B = 3200;
  char* ws = (char*)d_ws;
  const int fast = (ws_size >= TRI_B + WP_B + BP_B) ? 1 : 0;
  uint16_t* trit;
  uint16_t* wpk;
  float* bpk;
  if (fast) {
    trit = (uint16_t*)ws;
    wpk = (uint16_t*)(ws + TRI_B);
    bpk = (float*)(ws + TRI_B + WP_B);
  } else {
    trit = (uint16_t*)ws;  // unused
    wpk = (uint16_t*)ws;
    bpk = (float*)(ws + WP_B);
  }
  if (fast) k_tr<<<dim3(3072), dim3(256), 0, stream>>>(tri, trit);
  k_pack<<<dim3(45), dim3(256), 0, stream>>>(w_in, w_skip, w_bef, w_aft, w_out,
                                             b_in, b_skip, b_bef, b_aft, b_out,
                                             wpk, bpk);
  k_main<<<dim3(2048), dim3(256), 0, stream>>>(trit, tri, coords, wpk, bpk,
                                               (float*)d_out, fast);
}